// Round 13
// baseline (491.940 us; speedup 1.0000x reference)
//
#include <hip/hip_runtime.h>
#include <hip/hip_bf16.h>
#include <cstdint>

// ---------------------------------------------------------------------------
// SiameseGNN. R13: fc1 restructured for W-reuse -- one block per 32-row
// K-chunk (311 blocks), pooled rows for ALL 64 graphs staged in LDS, W
// column-slice in registers. fc1W read ONCE (was 64x = 326MB -> 97us).
// Keeps R12: radix CSR build (bhist/bscan/bpart/bfine), bf16 dinv-prescaled
// z rows, pure-gather agg128, separate gemm64b, fused dlast in agg64.
// ---------------------------------------------------------------------------

__device__ __forceinline__ int rfl(int v) { return __builtin_amdgcn_readfirstlane(v); }

__device__ __forceinline__ unsigned short f2bf(float f) {
    unsigned u = __float_as_uint(f);
    u = (u + 0x7fffu + ((u >> 16) & 1u)) >> 16;   // RNE
    return (unsigned short)u;
}
__device__ __forceinline__ float lo16(unsigned v) { return __uint_as_float(v << 16); }
__device__ __forceinline__ float hi16(unsigned v) { return __uint_as_float(v & 0xffff0000u); }

#define BSHIFT 7
#define BNODES 128
#define BCAP 3072

// ---------------- bhist: per-bucket edge counts (LDS-aggregated) -----------
__global__ void bhist_kernel(const int* __restrict__ dst, int* bcnt, int E, int nbuk) {
    __shared__ int bins[832];
    int t = threadIdx.x;
    for (int i = t; i < nbuk; i += 256) bins[i] = 0;
    __syncthreads();
    for (int e = blockIdx.x * 256 + t; e < E; e += gridDim.x * 256)
        atomicAdd(&bins[dst[e] >> BSHIFT], 1);
    __syncthreads();
    for (int i = t; i < nbuk; i += 256) {
        int v = bins[i];
        if (v) atomicAdd(&bcnt[i], v);
    }
}

// ---------------- bscan: bucket offsets + cursors (single wave) ------------
__global__ void bscan_kernel(const int* __restrict__ bcnt, int* __restrict__ boff,
                             int* __restrict__ bcur, int* __restrict__ off,
                             int nbuk, int E, int N1) {
    __shared__ int carry_s;
    int lane = threadIdx.x;   // 64 threads
    if (lane == 0) carry_s = 0;
    __syncthreads();
    for (int base = 0; base < nbuk; base += 64) {
        int i = base + lane;
        int v = (i < nbuk) ? bcnt[i] : 0;
        int s = v;
        for (int d2 = 1; d2 < 64; d2 <<= 1) { int u = __shfl_up(s, d2); if (lane >= d2) s += u; }
        int c = carry_s;
        if (i < nbuk) { boff[i] = c + s - v; bcur[i] = c + s - v; }
        __syncthreads();
        if (lane == 63) carry_s = c + s;
        __syncthreads();
    }
    if (lane == 0) { boff[nbuk] = E; off[N1] = E; }
}

// ---------------- bpart: partition edges into bucket-major staging ---------
#define BP_EPB 16384
__global__ __launch_bounds__(1024) void bpart_kernel(const int* __restrict__ dst,
                                                     const int* __restrict__ src,
                                                     const float* __restrict__ ew,
                                                     int* bcur, int2* __restrict__ stag,
                                                     int E, int nbuk) {
    __shared__ int cnt[832];
    __shared__ int base[832];
    int t = threadIdx.x;
    int e0 = blockIdx.x * BP_EPB;
    for (int i = t; i < nbuk; i += 1024) cnt[i] = 0;
    __syncthreads();
#pragma unroll
    for (int k = 0; k < 16; k++) {
        int e = e0 + k * 1024 + t;
        if (e < E) atomicAdd(&cnt[dst[e] >> BSHIFT], 1);
    }
    __syncthreads();
    for (int i = t; i < nbuk; i += 1024) {
        int c = cnt[i];
        base[i] = c ? atomicAdd(&bcur[i], c) : 0;
    }
    __syncthreads();
    for (int i = t; i < nbuk; i += 1024) cnt[i] = 0;
    __syncthreads();
#pragma unroll
    for (int k = 0; k < 16; k++) {
        int e = e0 + k * 1024 + t;
        if (e < E) {
            int d = dst[e];
            int b = d >> BSHIFT, dl = d & (BNODES - 1);
            int l = atomicAdd(&cnt[b], 1);
            stag[base[b] + l] = make_int2((src[e] & 0xFFFFF) | (dl << 20),
                                          __float_as_int(ew[e]));
        }
    }
}

// ---------------- bfine: bucket -> final CSR + off + dinv ------------------
__global__ __launch_bounds__(256) void bfine_kernel(const int2* __restrict__ stag,
                                                    const int* __restrict__ boff,
                                                    int2* __restrict__ packed,
                                                    int* __restrict__ off,
                                                    float* __restrict__ dinv,
                                                    int nbuk, int N1) {
    __shared__ int2 ein[BCAP];
    __shared__ int2 eout[BCAP];
    __shared__ float ews[BNODES];
    __shared__ int hist[BNODES];
    __shared__ int sb[BNODES];
    __shared__ int cnt2[BNODES];
    int b = blockIdx.x, t = threadIdx.x;
    int base = boff[b], nE = boff[b + 1] - base;
    bool staged = (nE <= BCAP);
    if (t < BNODES) { hist[t] = 0; ews[t] = 0.f; cnt2[t] = 0; }
    __syncthreads();
    if (staged)
        for (int i = t; i < nE; i += 256) ein[i] = stag[base + i];
    __syncthreads();
    for (int i = t; i < nE; i += 256) {
        int2 m = staged ? ein[i] : stag[base + i];
        int dl = m.x >> 20;
        atomicAdd(&hist[dl], 1);
        atomicAdd(&ews[dl], __int_as_float(m.y));
    }
    __syncthreads();
    if (t < 64) {
        int v0 = hist[t]; int s0 = v0;
        for (int d2 = 1; d2 < 64; d2 <<= 1) { int u = __shfl_up(s0, d2); if (t >= d2) s0 += u; }
        sb[t] = s0 - v0;
        int tot0 = __shfl(s0, 63);
        int v1 = hist[64 + t]; int s1 = v1;
        for (int d2 = 1; d2 < 64; d2 <<= 1) { int u = __shfl_up(s1, d2); if (t >= d2) s1 += u; }
        sb[64 + t] = tot0 + s1 - v1;
    }
    __syncthreads();
    int node = b * BNODES + t;
    if (t < BNODES && node < N1) {
        off[node] = base + sb[t];
        dinv[node] = rsqrtf(1.0f + ews[t]);   // +1 self loop
    }
    __syncthreads();
    for (int i = t; i < nE; i += 256) {
        int2 m = staged ? ein[i] : stag[base + i];
        int dl = m.x >> 20;
        int l = atomicAdd(&cnt2[dl], 1);
        int2 o = make_int2(m.x & 0xFFFFF, m.y);
        if (staged) eout[sb[dl] + l] = o;
        else packed[base + sb[dl] + l] = o;
    }
    __syncthreads();
    if (staged)
        for (int i = t; i < nE; i += 256) packed[base + i] = eout[i];
}

// ---------------- GEMM128: zs1 = bf16(dinv * (x @ Wg1)) --------------------
__global__ __launch_bounds__(256) void gemm128_kernel(const float* __restrict__ x,
                                                      const float* __restrict__ w,
                                                      const float* __restrict__ dinv,
                                                      unsigned short* __restrict__ outb,
                                                      int nrows) {
    __shared__ float ws[64 * 128];
    __shared__ float xs[64 * 68];
    int t = threadIdx.x;
    size_t r0 = (size_t)blockIdx.x * 64;
    int tx = t % 16, ty = t / 16;
    float acc[4][8];
#pragma unroll
    for (int i = 0; i < 4; i++)
#pragma unroll
        for (int j = 0; j < 8; j++) acc[i][j] = 0.f;

    for (int half = 0; half < 2; half++) {
        __syncthreads();
        for (int f = t; f < 64 * 32; f += 256)
            ((float4*)ws)[f] = ((const float4*)(w + half * 64 * 128))[f];
        for (int f = t; f < 64 * 16; f += 256) {
            int row = f >> 4, c4 = f & 15;
            float4 v = *((const float4*)(x + (r0 + row) * 128 + half * 64 + c4 * 4));
            *((float4*)(xs + row * 68 + c4 * 4)) = v;
        }
        __syncthreads();
        for (int k = 0; k < 64; k++) {
            float4 b0 = *((const float4*)(ws + k * 128 + tx * 8));
            float4 b1 = *((const float4*)(ws + k * 128 + tx * 8 + 4));
            float bb[8] = {b0.x, b0.y, b0.z, b0.w, b1.x, b1.y, b1.z, b1.w};
#pragma unroll
            for (int i = 0; i < 4; i++) {
                float a = xs[(ty * 4 + i) * 68 + k];
#pragma unroll
                for (int j = 0; j < 8; j++) acc[i][j] = fmaf(a, bb[j], acc[i][j]);
            }
        }
    }
#pragma unroll
    for (int i = 0; i < 4; i++) {
        size_t row = r0 + ty * 4 + i;
        float dv = dinv[row];
        uint4 pk;
        pk.x = (unsigned)f2bf(acc[i][0] * dv) | ((unsigned)f2bf(acc[i][1] * dv) << 16);
        pk.y = (unsigned)f2bf(acc[i][2] * dv) | ((unsigned)f2bf(acc[i][3] * dv) << 16);
        pk.z = (unsigned)f2bf(acc[i][4] * dv) | ((unsigned)f2bf(acc[i][5] * dv) << 16);
        pk.w = (unsigned)f2bf(acc[i][6] * dv) | ((unsigned)f2bf(acc[i][7] * dv) << 16);
        *((uint4*)(outb + row * 128 + tx * 8)) = pk;
    }
}

// ---------------- GEMM64b: zs2 = bf16(dinv * (h @ Wg2)), h f32 -------------
__global__ __launch_bounds__(256) void gemm64b_kernel(const float* __restrict__ x,
                                                      const float* __restrict__ w,
                                                      const float* __restrict__ dinv,
                                                      unsigned short* __restrict__ outb,
                                                      int nrows) {
    __shared__ float ws[64 * 64];
    __shared__ float xs[64 * 68];
    int t = threadIdx.x;
    size_t r0 = (size_t)blockIdx.x * 64;
    int tx = t % 8, ty = t / 8;    // TX=8, TY=32, AR=2
    float acc[2][8];
#pragma unroll
    for (int i = 0; i < 2; i++)
#pragma unroll
        for (int j = 0; j < 8; j++) acc[i][j] = 0.f;

    for (int half = 0; half < 2; half++) {
        __syncthreads();
        for (int f = t; f < 64 * 16; f += 256)
            ((float4*)ws)[f] = ((const float4*)(w + half * 64 * 64))[f];
        for (int f = t; f < 64 * 16; f += 256) {
            int row = f >> 4, c4 = f & 15;
            float4 v = *((const float4*)(x + (r0 + row) * 128 + half * 64 + c4 * 4));
            *((float4*)(xs + row * 68 + c4 * 4)) = v;
        }
        __syncthreads();
        for (int k = 0; k < 64; k++) {
            float4 b0 = *((const float4*)(ws + k * 64 + tx * 8));
            float4 b1 = *((const float4*)(ws + k * 64 + tx * 8 + 4));
            float bb[8] = {b0.x, b0.y, b0.z, b0.w, b1.x, b1.y, b1.z, b1.w};
#pragma unroll
            for (int i = 0; i < 2; i++) {
                float a = xs[(ty * 2 + i) * 68 + k];
#pragma unroll
                for (int j = 0; j < 8; j++) acc[i][j] = fmaf(a, bb[j], acc[i][j]);
            }
        }
    }
#pragma unroll
    for (int i = 0; i < 2; i++) {
        size_t row = r0 + ty * 2 + i;
        float dv = dinv[row];
        uint2 pk;
        pk.x = (unsigned)f2bf(acc[i][0] * dv) | ((unsigned)f2bf(acc[i][1] * dv) << 16);
        pk.y = (unsigned)f2bf(acc[i][2] * dv) | ((unsigned)f2bf(acc[i][3] * dv) << 16);
        *((uint2*)(outb + row * 64 + tx * 8)) = pk;
        pk.x = (unsigned)f2bf(acc[i][4] * dv) | ((unsigned)f2bf(acc[i][5] * dv) << 16);
        pk.y = (unsigned)f2bf(acc[i][6] * dv) | ((unsigned)f2bf(acc[i][7] * dv) << 16);
        *((uint2*)(outb + row * 64 + tx * 8 + 4)) = pk;
    }
}

// ---------------- agg layer1: PURE gather (bf16 in) -> h f32 ---------------
__global__ __launch_bounds__(256) void agg128_kernel(const unsigned short* __restrict__ zs,
                                                     const int2* __restrict__ packed,
                                                     const int* __restrict__ off,
                                                     const float* __restrict__ dinv,
                                                     const float* __restrict__ bias,
                                                     float* __restrict__ h, int n) {
    int wid = threadIdx.x >> 6;
    int lane = threadIdx.x & 63;
    int d = rfl(blockIdx.x * 4 + wid);
    if (d >= n) return;
    const unsigned short* zl = zs + lane * 2;
    float dv = dinv[d];
    unsigned sv = *((const unsigned*)(zl + (size_t)d * 128));
    float acc0 = lo16(sv), acc1 = hi16(sv);
    float2 bv = *((const float2*)(bias + lane * 2));
    int e0 = off[d], e1 = off[d + 1];
    int e = e0;
    for (; e + 4 <= e1; e += 4) {
        int2 m0 = packed[e], m1 = packed[e + 1], m2 = packed[e + 2], m3 = packed[e + 3];
        int s0 = rfl(m0.x), s1 = rfl(m1.x), s2i = rfl(m2.x), s3 = rfl(m3.x);
        float w0 = __int_as_float(rfl(m0.y)), w1 = __int_as_float(rfl(m1.y));
        float w2v = __int_as_float(rfl(m2.y)), w3 = __int_as_float(rfl(m3.y));
        unsigned v0 = *((const unsigned*)(zl + (size_t)s0 * 128));
        unsigned v1 = *((const unsigned*)(zl + (size_t)s1 * 128));
        unsigned v2 = *((const unsigned*)(zl + (size_t)s2i * 128));
        unsigned v3 = *((const unsigned*)(zl + (size_t)s3 * 128));
        acc0 = fmaf(w0, lo16(v0), acc0); acc1 = fmaf(w0, hi16(v0), acc1);
        acc0 = fmaf(w1, lo16(v1), acc0); acc1 = fmaf(w1, hi16(v1), acc1);
        acc0 = fmaf(w2v, lo16(v2), acc0); acc1 = fmaf(w2v, hi16(v2), acc1);
        acc0 = fmaf(w3, lo16(v3), acc0); acc1 = fmaf(w3, hi16(v3), acc1);
    }
    for (; e < e1; e++) {
        int2 m = packed[e];
        int s = rfl(m.x);
        float w = __int_as_float(rfl(m.y));
        unsigned v = *((const unsigned*)(zl + (size_t)s * 128));
        acc0 = fmaf(w, lo16(v), acc0);
        acc1 = fmaf(w, hi16(v), acc1);
    }
    float2 hv = {fmaxf(dv * acc0 + bv.x, 0.f), fmaxf(dv * acc1 + bv.y, 0.f)};
    *((float2*)(h + (size_t)d * 128 + lane * 2)) = hv;
}

// ---------------- agg layer2 (bf16 in) + fused dlast -----------------------
__global__ __launch_bounds__(256) void agg64_kernel(const unsigned short* __restrict__ zs2,
                                                    const int2* __restrict__ packed,
                                                    const int* __restrict__ off,
                                                    const float* __restrict__ dinv,
                                                    const float* __restrict__ bias,
                                                    float* __restrict__ o1buf, int n,
                                                    const float* __restrict__ o2,
                                                    const float* __restrict__ s2,
                                                    float* __restrict__ dlast, int N2) {
    int wid = threadIdx.x >> 6;
    int lane = threadIdx.x & 63;
    int d = rfl(blockIdx.x * 4 + wid);
    if (d >= n) return;
    const unsigned short* zl = zs2 + lane;
    float dv = dinv[d];
    float acc0 = __uint_as_float((unsigned)zl[(size_t)d * 64] << 16);
    float b0 = bias[lane];
    int e0 = off[d], e1 = off[d + 1];
    int e = e0;
    for (; e + 4 <= e1; e += 4) {
        int2 m0 = packed[e], m1 = packed[e + 1], m2 = packed[e + 2], m3 = packed[e + 3];
        int s0 = rfl(m0.x), s1 = rfl(m1.x), s2i = rfl(m2.x), s3 = rfl(m3.x);
        float w0 = __int_as_float(rfl(m0.y)), w1 = __int_as_float(rfl(m1.y));
        float w2v = __int_as_float(rfl(m2.y)), w3 = __int_as_float(rfl(m3.y));
        float v0 = __uint_as_float((unsigned)zl[(size_t)s0 * 64] << 16);
        float v1 = __uint_as_float((unsigned)zl[(size_t)s1 * 64] << 16);
        float v2 = __uint_as_float((unsigned)zl[(size_t)s2i * 64] << 16);
        float v3 = __uint_as_float((unsigned)zl[(size_t)s3 * 64] << 16);
        acc0 = fmaf(w0, v0, acc0);
        acc0 = fmaf(w1, v1, acc0);
        acc0 = fmaf(w2v, v2, acc0);
        acc0 = fmaf(w3, v3, acc0);
    }
    for (; e < e1; e++) {
        int2 m = packed[e];
        int s = rfl(m.x);
        float w = __int_as_float(rfl(m.y));
        acc0 = fmaf(w, __uint_as_float((unsigned)zl[(size_t)s * 64] << 16), acc0);
    }
    float a = fmaxf(dv * acc0 + b0, 0.f);
    o1buf[(size_t)d * 64 + lane] = a;
    float bl = o2[(size_t)(N2 - 1) * 64 + lane];
    float aa = a * a, ab = a * bl;
    for (int dd = 32; dd >= 1; dd >>= 1) {
        aa += __shfl_xor(aa, dd);
        ab += __shfl_xor(ab, dd);
    }
    if (lane == 0) {
        float d2 = aa + s2[N2 - 1] - 2.f * ab;
        dlast[d] = sqrtf(fmaxf(d2, 0.f) + 1e-12f);
    }
}

// ---------------- graph2 (row-major f32, tiny, multi-kernel) ---------------
__global__ void g2_prep(const int* __restrict__ ei2, const float* __restrict__ ew2,
                        float* dinv2, float* a2a, float* a2b, int E2, int N2) {
    __shared__ float degl[256];
    int t = threadIdx.x;
    degl[t] = 1.0f;
    __syncthreads();
    for (int e = t; e < E2; e += 256) atomicAdd(&degl[ei2[E2 + e]], ew2[e]);
    __syncthreads();
    if (t < N2) dinv2[t] = rsqrtf(degl[t]);
    for (int i = t; i < N2 * 128; i += 256) a2a[i] = 0.f;
    for (int i = t; i < N2 * 64; i += 256) a2b[i] = 0.f;
}

template <int NCOL>
__global__ void g2_gemm(const float* __restrict__ x, const float* __restrict__ w,
                        float* __restrict__ z, int N2) {
    __shared__ float xr[128];
    int row = blockIdx.x, t = threadIdx.x;
    for (int k = t; k < 128; k += NCOL) xr[k] = x[row * 128 + k];
    __syncthreads();
    float acc = 0.f;
    for (int k = 0; k < 128; k++) acc = fmaf(xr[k], w[k * NCOL + t], acc);
    z[row * NCOL + t] = acc;
}

template <int C>
__global__ void g2_scatter(const float* __restrict__ z, const int* __restrict__ ei2,
                           const float* __restrict__ ew2, const float* __restrict__ dinv2,
                           float* a2, int E2) {
    constexpr int CPL = C / 64;
    int wid = threadIdx.x >> 6, lane = threadIdx.x & 63;
    int e = blockIdx.x * 4 + wid;
    if (e >= E2) return;
    int s = ei2[e], d = ei2[E2 + e];
    float nm = dinv2[s] * ew2[e] * dinv2[d];
#pragma unroll
    for (int q = 0; q < CPL; q++) {
        int c = lane * CPL + q;
        atomicAdd(&a2[d * C + c], nm * z[s * C + c]);
    }
}

__global__ void g2_fin128(const float* __restrict__ a2, const float* __restrict__ z,
                          const float* __restrict__ dinv2, const float* __restrict__ bias,
                          float* __restrict__ out, int N2) {
    int i = blockIdx.x * 256 + threadIdx.x;
    if (i >= N2 * 128) return;
    int n = i / 128, c = i % 128;
    float dv = dinv2[n];
    out[i] = fmaxf(a2[i] + dv * dv * z[i] + bias[c], 0.f);
}

__global__ void g2_fin64s2(const float* __restrict__ a2, const float* __restrict__ z,
                           const float* __restrict__ dinv2, const float* __restrict__ bias,
                           float* __restrict__ out, float* __restrict__ s2, int N2) {
    int wid = threadIdx.x >> 6, lane = threadIdx.x & 63;
    int row = blockIdx.x * 4 + wid;
    if (row >= N2) return;
    int i = row * 64 + lane;
    float dv = dinv2[row];
    float v = fmaxf(a2[i] + dv * dv * z[i] + bias[lane], 0.f);
    out[i] = v;
    float ss = v * v;
    for (int d = 32; d >= 1; d >>= 1) ss += __shfl_xor(ss, d);
    if (lane == 0) s2[row] = ss;
}

// ---------------- top-K per graph (wave-shfl argmax, stable ties) ----------
__global__ __launch_bounds__(256) void topk_kernel(const float* __restrict__ dlast,
                                                   int* __restrict__ topidx,
                                                   int NPG, int K) {
    __shared__ unsigned long long keys[1600];
    __shared__ unsigned long long wmax[4];
    int g = blockIdx.x, t = threadIdx.x;
    int lane = t & 63, wid = t >> 6;
    for (int r = t; r < NPG; r += 256) {
        unsigned vb = __float_as_uint(dlast[(size_t)g * NPG + r]);  // dist > 0
        keys[r] = ((unsigned long long)vb << 32) | (unsigned)(NPG - 1 - r);
    }
    __syncthreads();
    for (int it = 0; it < K; it++) {
        unsigned long long m = 0ull;
        for (int r = t; r < NPG; r += 256) { unsigned long long k = keys[r]; if (k > m) m = k; }
        for (int d = 32; d >= 1; d >>= 1) {
            unsigned long long u = __shfl_xor(m, d);
            if (u > m) m = u;
        }
        if (lane == 0) wmax[wid] = m;
        __syncthreads();
        if (t == 0) {
            unsigned long long mm = wmax[0];
            for (int w = 1; w < 4; w++) if (wmax[w] > mm) mm = wmax[w];
            int rbest = NPG - 1 - (int)(mm & 0xffffffffull);
            topidx[g * K + it] = rbest;
            keys[rbest] = 0ull;
        }
        __syncthreads();
    }
}

// ---------------- pooled rows: dist(o1[sel], o2[j]) for j<N2 ---------------
__global__ void pooled_kernel(const float* __restrict__ o1, const float* __restrict__ o2,
                              const float* __restrict__ s2, const int* __restrict__ topidx,
                              float* __restrict__ pooled, int NPG, int K, int N2) {
    __shared__ float o1s[64];
    __shared__ float s1sh;
    int g = blockIdx.x / K, kk = blockIdx.x % K;
    int t = threadIdx.x;
    int r = topidx[g * K + kk];
    size_t node = (size_t)g * NPG + r;
    if (t < 64) o1s[t] = o1[node * 64 + t];
    __syncthreads();
    if (t < 64) {
        float v = o1s[t]; float ss = v * v;
        for (int d = 32; d >= 1; d >>= 1) ss += __shfl_xor(ss, d);
        if (t == 0) s1sh = ss;
    }
    __syncthreads();
    if (t < N2) {
        float dot = 0.f;
#pragma unroll 8
        for (int k2 = 0; k2 < 64; k2++) dot = fmaf(o1s[k2], o2[t * 64 + k2], dot);
        float d2 = s1sh + s2[t] - 2.f * dot;
        pooled[(size_t)blockIdx.x * N2 + t] = sqrtf(fmaxf(d2, 0.f) + 1e-12f);
    }
}

// ---------------- fc1: one block per 32-row K-chunk, all 64 graphs ---------
// fc1W read exactly once. W column-slice in registers; pooled rows in LDS.
#define FC1_CH 32
__global__ __launch_bounds__(256) void fc1_kernel(const float* __restrict__ pooled,
                                                  const float* __restrict__ fc1W,
                                                  float* __restrict__ h1p,
                                                  int PK, int NCHUNK, int B) {
    __shared__ float ps[64][FC1_CH];
    int ch = blockIdx.x;
    int r0 = ch * FC1_CH;
    int nr = min(FC1_CH, PK - r0);
    int t = threadIdx.x;
    for (int f = t; f < 64 * FC1_CH; f += 256) {
        int b = f / FC1_CH, r = f % FC1_CH;
        ps[b][r] = (r < nr && b < B) ? pooled[(size_t)b * PK + r0 + r] : 0.f;
    }
    int c = t & 127, bh = t >> 7;
    float wreg[FC1_CH];
#pragma unroll
    for (int r = 0; r < FC1_CH; r++)
        wreg[r] = (r < nr) ? fc1W[(size_t)(r0 + r) * 128 + c] : 0.f;
    __syncthreads();
    for (int bb = 0; bb < 32; bb++) {
        int b = bh * 32 + bb;
        float acc = 0.f;
#pragma unroll
        for (int r = 0; r < FC1_CH; r++) acc = fmaf(ps[b][r], wreg[r], acc);
        if (b < B) h1p[((size_t)b * NCHUNK + ch) * 128 + c] = acc;
    }
}

// ---------------- head tail ------------------------------------------------
__global__ __launch_bounds__(256) void head2_kernel(
    const float* __restrict__ h1p, int NCHUNK,
    const float* __restrict__ fc1b, const float* __restrict__ ln1g,
    const float* __restrict__ ln1b, const float* __restrict__ fc2W,
    const float* __restrict__ fc2b, const float* __restrict__ ln2g,
    const float* __restrict__ ln2b, const float* __restrict__ fc3W,
    const float* __restrict__ fc3b, float* __restrict__ out) {
    __shared__ float red[256];
    __shared__ float h1[128];
    __shared__ float h2[64];
    int b = blockIdx.x, t = threadIdx.x;
    if (t < 128) {
        float s = 0.f;
        for (int ch = 0; ch < NCHUNK; ch++)
            s += h1p[((size_t)b * NCHUNK + ch) * 128 + t];
        h1[t] = s + fc1b[t];
    }
    __syncthreads();
    red[t] = (t < 128) ? h1[t] : 0.f;
    __syncthreads();
    for (int s = 128; s >= 1; s >>= 1) { if (t < s) red[t] += red[t + s]; __syncthreads(); }
    float mean1 = red[0] / 128.f;
    __syncthreads();
    float dv1 = (t < 128) ? (h1[t] - mean1) : 0.f;
    red[t] = dv1 * dv1;
    __syncthreads();
    for (int s = 128; s >= 1; s >>= 1) { if (t < s) red[t] += red[t + s]; __syncthreads(); }
    float var1 = red[0] / 128.f;
    __syncthreads();
    if (t < 128) {
        float y = (h1[t] - mean1) * rsqrtf(var1 + 1e-5f) * ln1g[t] + ln1b[t];
        h1[t] = fmaxf(y, 0.f);
    }
    __syncthreads();
    if (t < 64) {
        float a2v = 0.f;
        for (int k2 = 0; k2 < 128; k2++) a2v = fmaf(h1[k2], fc2W[k2 * 64 + t], a2v);
        h2[t] = a2v + fc2b[t];
    }
    __syncthreads();
    red[t] = (t < 64) ? h2[t] : 0.f;
    __syncthreads();
    for (int s = 128; s >= 1; s >>= 1) { if (t < s) red[t] += red[t + s]; __syncthreads(); }
    float mean2 = red[0] / 64.f;
    __syncthreads();
    float dv2 = (t < 64) ? (h2[t] - mean2) : 0.f;
    red[t] = dv2 * dv2;
    __syncthreads();
    for (int s = 128; s >= 1; s >>= 1) { if (t < s) red[t] += red[t + s]; __syncthreads(); }
    float var2 = red[0] / 64.f;
    __syncthreads();
    if (t < 64)
        h2[t] = fmaxf((h2[t] - mean2) * rsqrtf(var2 + 1e-5f) * ln2g[t] + ln2b[t], 0.f);
    __syncthreads();
    red[t] = (t < 64) ? h2[t] * fc3W[t] : 0.f;
    __syncthreads();
    for (int s = 128; s >= 1; s >>= 1) { if (t < s) red[t] += red[t + s]; __syncthreads(); }
    if (t == 0) out[b] = 1.f / (1.f + expf(-(red[0] + fc3b[0])));
}

// ---------------------------------------------------------------------------
extern "C" void kernel_launch(void* const* d_in, const int* in_sizes, int n_in,
                              void* d_out, int out_size, void* d_ws, size_t ws_size,
                              hipStream_t stream) {
    const float* x1   = (const float*)d_in[0];
    const float* ew1  = (const float*)d_in[1];
    const float* x2   = (const float*)d_in[2];
    const float* ew2  = (const float*)d_in[3];
    const float* Wg1  = (const float*)d_in[4];
    const float* bg1  = (const float*)d_in[5];
    const float* Wg2  = (const float*)d_in[6];
    const float* bg2  = (const float*)d_in[7];
    const float* fc1W = (const float*)d_in[8];
    const float* fc1b = (const float*)d_in[9];
    const float* ln1g = (const float*)d_in[10];
    const float* ln1b = (const float*)d_in[11];
    const float* fc2W = (const float*)d_in[12];
    const float* fc2b = (const float*)d_in[13];
    const float* ln2g = (const float*)d_in[14];
    const float* ln2b = (const float*)d_in[15];
    const float* fc3W = (const float*)d_in[16];
    const float* fc3b = (const float*)d_in[17];
    const int* ei1    = (const int*)d_in[18];
    const int* ei2    = (const int*)d_in[19];
    float* out = (float*)d_out;

    const int N1 = in_sizes[0] / 128;        // 102400
    const int E1 = in_sizes[1];              // 1638400
    const int N2 = in_sizes[2] / 128;        // 199
    const int E2 = in_sizes[3];              // 3184
    const int B  = out_size;                 // 64
    const int NPG = N1 / B;                  // 1600
    const int K  = (in_sizes[8] / 128) / N2; // 50
    const int PK = K * N2;                   // 9950
    const int NCHUNK = (PK + FC1_CH - 1) / FC1_CH;  // 311
    const int NBUK = (N1 + BNODES - 1) / BNODES;    // 800

    char* wsb = (char*)d_ws;
    size_t o = 0;
    auto alloc = [&](size_t bytes) -> void* {
        void* p = wsb + o;
        o += (bytes + 255) & ~(size_t)255;
        return p;
    };
    int*   bcnt   = (int*)alloc((size_t)NBUK * 4);
    int*   boff   = (int*)alloc((size_t)(NBUK + 1) * 4);
    int*   bcur   = (int*)alloc((size_t)NBUK * 4);
    int2*  stag   = (int2*)alloc((size_t)E1 * 8);
    int2*  packed = (int2*)alloc((size_t)E1 * 8);
    int*   off    = (int*)alloc((size_t)(N1 + 1) * 4);
    float* dinv1  = (float*)alloc((size_t)N1 * 4);
    unsigned short* zs1 = (unsigned short*)alloc((size_t)N1 * 128 * 2);
    float* h      = (float*)alloc((size_t)N1 * 128 * 4);
    unsigned short* zs2 = (unsigned short*)alloc((size_t)N1 * 64 * 2);
    float* o1buf  = (float*)alloc((size_t)N1 * 64 * 4);
    float* dl     = (float*)alloc((size_t)N1 * 4);
    int*   tki    = (int*)alloc((size_t)B * K * 4);
    float* pooled = (float*)alloc((size_t)B * K * N2 * 4);
    float* h1p    = (float*)alloc((size_t)B * NCHUNK * 128 * 4);
    float* dinv2  = (float*)alloc((size_t)N2 * 4);
    float* z2g    = (float*)alloc((size_t)N2 * 128 * 4);
    float* h2b    = (float*)alloc((size_t)N2 * 128 * 4);
    float* a2a    = (float*)alloc((size_t)N2 * 128 * 4);
    float* zz2    = (float*)alloc((size_t)N2 * 64 * 4);
    float* a2b    = (float*)alloc((size_t)N2 * 64 * 4);
    float* o2b    = (float*)alloc((size_t)N2 * 64 * 4);
    float* s2     = (float*)alloc((size_t)N2 * 4);
    (void)ws_size; (void)n_in;

    const int* src1 = ei1;
    const int* dst1 = ei1 + E1;

    // -------- graph1 CSR build (radix partition) --------
    hipMemsetAsync(bcnt, 0, (size_t)NBUK * 4, stream);
    bhist_kernel<<<400, 256, 0, stream>>>(dst1, bcnt, E1, NBUK);
    bscan_kernel<<<1, 64, 0, stream>>>(bcnt, boff, bcur, off, NBUK, E1, N1);
    bpart_kernel<<<(E1 + BP_EPB - 1) / BP_EPB, 1024, 0, stream>>>(dst1, src1, ew1, bcur,
                                                                  stag, E1, NBUK);
    bfine_kernel<<<NBUK, 256, 0, stream>>>(stag, boff, packed, off, dinv1, NBUK, N1);

    // -------- graph1 layer 1 + layer-2 GEMM --------
    gemm128_kernel<<<N1 / 64, 256, 0, stream>>>(x1, Wg1, dinv1, zs1, N1);
    agg128_kernel<<<N1 / 4, 256, 0, stream>>>(zs1, packed, off, dinv1, bg1, h, N1);
    gemm64b_kernel<<<N1 / 64, 256, 0, stream>>>(h, Wg2, dinv1, zs2, N1);

    // -------- graph2 GNN (multi-kernel, parallel) --------
    g2_prep<<<1, 256, 0, stream>>>(ei2, ew2, dinv2, a2a, a2b, E2, N2);
    g2_gemm<128><<<N2, 128, 0, stream>>>(x2, Wg1, z2g, N2);
    g2_scatter<128><<<(E2 + 3) / 4, 256, 0, stream>>>(z2g, ei2, ew2, dinv2, a2a, E2);
    g2_fin128<<<(N2 * 128 + 255) / 256, 256, 0, stream>>>(a2a, z2g, dinv2, bg1, h2b, N2);
    g2_gemm<64><<<N2, 64, 0, stream>>>(h2b, Wg2, zz2, N2);
    g2_scatter<64><<<(E2 + 3) / 4, 256, 0, stream>>>(zz2, ei2, ew2, dinv2, a2b, E2);
    g2_fin64s2<<<(N2 + 3) / 4, 256, 0, stream>>>(a2b, zz2, dinv2, bg2, o2b, s2, N2);

    // -------- graph1 layer 2 agg + fused dlast --------
    agg64_kernel<<<N1 / 4, 256, 0, stream>>>(zs2, packed, off, dinv1, bg2, o1buf, N1,
                                             o2b, s2, dl, N2);

    // -------- SortAggregation + head --------
    topk_kernel<<<B, 256, 0, stream>>>(dl, tki, NPG, K);
    pooled_kernel<<<B * K, 256, 0, stream>>>(o1buf, o2b, s2, tki, pooled, NPG, K, N2);
    fc1_kernel<<<NCHUNK, 256, 0, stream>>>(pooled, fc1W, h1p, PK, NCHUNK, B);
    head2_kernel<<<B, 256, 0, stream>>>(h1p, NCHUNK, fc1b, ln1g, ln1b, fc2W, fc2b,
                                        ln2g, ln2b, fc3W, fc3b, out);
}

// Round 14
// 421.605 us; speedup vs baseline: 1.1668x; 1.1668x over previous
//
#include <hip/hip_runtime.h>
#include <hip/hip_bf16.h>
#include <cstdint>

// ---------------------------------------------------------------------------
// SiameseGNN. R14: head2's serial 311-partial reduce (80us, 64 blocks @2.5%
// occupancy) split into fc1red -- one WAVE per output element (8192 waves),
// lane-parallel chunk sum + shfl tree + bias -> h1full. head2 reads h1full.
// Keeps R13: W-reuse fc1 (one block/K-chunk), radix CSR build, bf16 rows,
// pure-gather agg128, gemm64b, fused dlast agg64.
// ---------------------------------------------------------------------------

__device__ __forceinline__ int rfl(int v) { return __builtin_amdgcn_readfirstlane(v); }

__device__ __forceinline__ unsigned short f2bf(float f) {
    unsigned u = __float_as_uint(f);
    u = (u + 0x7fffu + ((u >> 16) & 1u)) >> 16;   // RNE
    return (unsigned short)u;
}
__device__ __forceinline__ float lo16(unsigned v) { return __uint_as_float(v << 16); }
__device__ __forceinline__ float hi16(unsigned v) { return __uint_as_float(v & 0xffff0000u); }

#define BSHIFT 7
#define BNODES 128
#define BCAP 3072

// ---------------- bhist: per-bucket edge counts (LDS-aggregated) -----------
__global__ void bhist_kernel(const int* __restrict__ dst, int* bcnt, int E, int nbuk) {
    __shared__ int bins[832];
    int t = threadIdx.x;
    for (int i = t; i < nbuk; i += 256) bins[i] = 0;
    __syncthreads();
    for (int e = blockIdx.x * 256 + t; e < E; e += gridDim.x * 256)
        atomicAdd(&bins[dst[e] >> BSHIFT], 1);
    __syncthreads();
    for (int i = t; i < nbuk; i += 256) {
        int v = bins[i];
        if (v) atomicAdd(&bcnt[i], v);
    }
}

// ---------------- bscan: bucket offsets + cursors (single wave) ------------
__global__ void bscan_kernel(const int* __restrict__ bcnt, int* __restrict__ boff,
                             int* __restrict__ bcur, int* __restrict__ off,
                             int nbuk, int E, int N1) {
    __shared__ int carry_s;
    int lane = threadIdx.x;   // 64 threads
    if (lane == 0) carry_s = 0;
    __syncthreads();
    for (int base = 0; base < nbuk; base += 64) {
        int i = base + lane;
        int v = (i < nbuk) ? bcnt[i] : 0;
        int s = v;
        for (int d2 = 1; d2 < 64; d2 <<= 1) { int u = __shfl_up(s, d2); if (lane >= d2) s += u; }
        int c = carry_s;
        if (i < nbuk) { boff[i] = c + s - v; bcur[i] = c + s - v; }
        __syncthreads();
        if (lane == 63) carry_s = c + s;
        __syncthreads();
    }
    if (lane == 0) { boff[nbuk] = E; off[N1] = E; }
}

// ---------------- bpart: partition edges into bucket-major staging ---------
#define BP_EPB 16384
__global__ __launch_bounds__(1024) void bpart_kernel(const int* __restrict__ dst,
                                                     const int* __restrict__ src,
                                                     const float* __restrict__ ew,
                                                     int* bcur, int2* __restrict__ stag,
                                                     int E, int nbuk) {
    __shared__ int cnt[832];
    __shared__ int base[832];
    int t = threadIdx.x;
    int e0 = blockIdx.x * BP_EPB;
    for (int i = t; i < nbuk; i += 1024) cnt[i] = 0;
    __syncthreads();
#pragma unroll
    for (int k = 0; k < 16; k++) {
        int e = e0 + k * 1024 + t;
        if (e < E) atomicAdd(&cnt[dst[e] >> BSHIFT], 1);
    }
    __syncthreads();
    for (int i = t; i < nbuk; i += 1024) {
        int c = cnt[i];
        base[i] = c ? atomicAdd(&bcur[i], c) : 0;
    }
    __syncthreads();
    for (int i = t; i < nbuk; i += 1024) cnt[i] = 0;
    __syncthreads();
#pragma unroll
    for (int k = 0; k < 16; k++) {
        int e = e0 + k * 1024 + t;
        if (e < E) {
            int d = dst[e];
            int b = d >> BSHIFT, dl = d & (BNODES - 1);
            int l = atomicAdd(&cnt[b], 1);
            stag[base[b] + l] = make_int2((src[e] & 0xFFFFF) | (dl << 20),
                                          __float_as_int(ew[e]));
        }
    }
}

// ---------------- bfine: bucket -> final CSR + off + dinv ------------------
__global__ __launch_bounds__(256) void bfine_kernel(const int2* __restrict__ stag,
                                                    const int* __restrict__ boff,
                                                    int2* __restrict__ packed,
                                                    int* __restrict__ off,
                                                    float* __restrict__ dinv,
                                                    int nbuk, int N1) {
    __shared__ int2 ein[BCAP];
    __shared__ int2 eout[BCAP];
    __shared__ float ews[BNODES];
    __shared__ int hist[BNODES];
    __shared__ int sb[BNODES];
    __shared__ int cnt2[BNODES];
    int b = blockIdx.x, t = threadIdx.x;
    int base = boff[b], nE = boff[b + 1] - base;
    bool staged = (nE <= BCAP);
    if (t < BNODES) { hist[t] = 0; ews[t] = 0.f; cnt2[t] = 0; }
    __syncthreads();
    if (staged)
        for (int i = t; i < nE; i += 256) ein[i] = stag[base + i];
    __syncthreads();
    for (int i = t; i < nE; i += 256) {
        int2 m = staged ? ein[i] : stag[base + i];
        int dl = m.x >> 20;
        atomicAdd(&hist[dl], 1);
        atomicAdd(&ews[dl], __int_as_float(m.y));
    }
    __syncthreads();
    if (t < 64) {
        int v0 = hist[t]; int s0 = v0;
        for (int d2 = 1; d2 < 64; d2 <<= 1) { int u = __shfl_up(s0, d2); if (t >= d2) s0 += u; }
        sb[t] = s0 - v0;
        int tot0 = __shfl(s0, 63);
        int v1 = hist[64 + t]; int s1 = v1;
        for (int d2 = 1; d2 < 64; d2 <<= 1) { int u = __shfl_up(s1, d2); if (t >= d2) s1 += u; }
        sb[64 + t] = tot0 + s1 - v1;
    }
    __syncthreads();
    int node = b * BNODES + t;
    if (t < BNODES && node < N1) {
        off[node] = base + sb[t];
        dinv[node] = rsqrtf(1.0f + ews[t]);   // +1 self loop
    }
    __syncthreads();
    for (int i = t; i < nE; i += 256) {
        int2 m = staged ? ein[i] : stag[base + i];
        int dl = m.x >> 20;
        int l = atomicAdd(&cnt2[dl], 1);
        int2 o = make_int2(m.x & 0xFFFFF, m.y);
        if (staged) eout[sb[dl] + l] = o;
        else packed[base + sb[dl] + l] = o;
    }
    __syncthreads();
    if (staged)
        for (int i = t; i < nE; i += 256) packed[base + i] = eout[i];
}

// ---------------- GEMM128: zs1 = bf16(dinv * (x @ Wg1)) --------------------
__global__ __launch_bounds__(256) void gemm128_kernel(const float* __restrict__ x,
                                                      const float* __restrict__ w,
                                                      const float* __restrict__ dinv,
                                                      unsigned short* __restrict__ outb,
                                                      int nrows) {
    __shared__ float ws[64 * 128];
    __shared__ float xs[64 * 68];
    int t = threadIdx.x;
    size_t r0 = (size_t)blockIdx.x * 64;
    int tx = t % 16, ty = t / 16;
    float acc[4][8];
#pragma unroll
    for (int i = 0; i < 4; i++)
#pragma unroll
        for (int j = 0; j < 8; j++) acc[i][j] = 0.f;

    for (int half = 0; half < 2; half++) {
        __syncthreads();
        for (int f = t; f < 64 * 32; f += 256)
            ((float4*)ws)[f] = ((const float4*)(w + half * 64 * 128))[f];
        for (int f = t; f < 64 * 16; f += 256) {
            int row = f >> 4, c4 = f & 15;
            float4 v = *((const float4*)(x + (r0 + row) * 128 + half * 64 + c4 * 4));
            *((float4*)(xs + row * 68 + c4 * 4)) = v;
        }
        __syncthreads();
        for (int k = 0; k < 64; k++) {
            float4 b0 = *((const float4*)(ws + k * 128 + tx * 8));
            float4 b1 = *((const float4*)(ws + k * 128 + tx * 8 + 4));
            float bb[8] = {b0.x, b0.y, b0.z, b0.w, b1.x, b1.y, b1.z, b1.w};
#pragma unroll
            for (int i = 0; i < 4; i++) {
                float a = xs[(ty * 4 + i) * 68 + k];
#pragma unroll
                for (int j = 0; j < 8; j++) acc[i][j] = fmaf(a, bb[j], acc[i][j]);
            }
        }
    }
#pragma unroll
    for (int i = 0; i < 4; i++) {
        size_t row = r0 + ty * 4 + i;
        float dv = dinv[row];
        uint4 pk;
        pk.x = (unsigned)f2bf(acc[i][0] * dv) | ((unsigned)f2bf(acc[i][1] * dv) << 16);
        pk.y = (unsigned)f2bf(acc[i][2] * dv) | ((unsigned)f2bf(acc[i][3] * dv) << 16);
        pk.z = (unsigned)f2bf(acc[i][4] * dv) | ((unsigned)f2bf(acc[i][5] * dv) << 16);
        pk.w = (unsigned)f2bf(acc[i][6] * dv) | ((unsigned)f2bf(acc[i][7] * dv) << 16);
        *((uint4*)(outb + row * 128 + tx * 8)) = pk;
    }
}

// ---------------- GEMM64b: zs2 = bf16(dinv * (h @ Wg2)), h f32 -------------
__global__ __launch_bounds__(256) void gemm64b_kernel(const float* __restrict__ x,
                                                      const float* __restrict__ w,
                                                      const float* __restrict__ dinv,
                                                      unsigned short* __restrict__ outb,
                                                      int nrows) {
    __shared__ float ws[64 * 64];
    __shared__ float xs[64 * 68];
    int t = threadIdx.x;
    size_t r0 = (size_t)blockIdx.x * 64;
    int tx = t % 8, ty = t / 8;    // TX=8, TY=32, AR=2
    float acc[2][8];
#pragma unroll
    for (int i = 0; i < 2; i++)
#pragma unroll
        for (int j = 0; j < 8; j++) acc[i][j] = 0.f;

    for (int half = 0; half < 2; half++) {
        __syncthreads();
        for (int f = t; f < 64 * 16; f += 256)
            ((float4*)ws)[f] = ((const float4*)(w + half * 64 * 64))[f];
        for (int f = t; f < 64 * 16; f += 256) {
            int row = f >> 4, c4 = f & 15;
            float4 v = *((const float4*)(x + (r0 + row) * 128 + half * 64 + c4 * 4));
            *((float4*)(xs + row * 68 + c4 * 4)) = v;
        }
        __syncthreads();
        for (int k = 0; k < 64; k++) {
            float4 b0 = *((const float4*)(ws + k * 64 + tx * 8));
            float4 b1 = *((const float4*)(ws + k * 64 + tx * 8 + 4));
            float bb[8] = {b0.x, b0.y, b0.z, b0.w, b1.x, b1.y, b1.z, b1.w};
#pragma unroll
            for (int i = 0; i < 2; i++) {
                float a = xs[(ty * 2 + i) * 68 + k];
#pragma unroll
                for (int j = 0; j < 8; j++) acc[i][j] = fmaf(a, bb[j], acc[i][j]);
            }
        }
    }
#pragma unroll
    for (int i = 0; i < 2; i++) {
        size_t row = r0 + ty * 2 + i;
        float dv = dinv[row];
        uint2 pk;
        pk.x = (unsigned)f2bf(acc[i][0] * dv) | ((unsigned)f2bf(acc[i][1] * dv) << 16);
        pk.y = (unsigned)f2bf(acc[i][2] * dv) | ((unsigned)f2bf(acc[i][3] * dv) << 16);
        *((uint2*)(outb + row * 64 + tx * 8)) = pk;
        pk.x = (unsigned)f2bf(acc[i][4] * dv) | ((unsigned)f2bf(acc[i][5] * dv) << 16);
        pk.y = (unsigned)f2bf(acc[i][6] * dv) | ((unsigned)f2bf(acc[i][7] * dv) << 16);
        *((uint2*)(outb + row * 64 + tx * 8 + 4)) = pk;
    }
}

// ---------------- agg layer1: PURE gather (bf16 in) -> h f32 ---------------
__global__ __launch_bounds__(256) void agg128_kernel(const unsigned short* __restrict__ zs,
                                                     const int2* __restrict__ packed,
                                                     const int* __restrict__ off,
                                                     const float* __restrict__ dinv,
                                                     const float* __restrict__ bias,
                                                     float* __restrict__ h, int n) {
    int wid = threadIdx.x >> 6;
    int lane = threadIdx.x & 63;
    int d = rfl(blockIdx.x * 4 + wid);
    if (d >= n) return;
    const unsigned short* zl = zs + lane * 2;
    float dv = dinv[d];
    unsigned sv = *((const unsigned*)(zl + (size_t)d * 128));
    float acc0 = lo16(sv), acc1 = hi16(sv);
    float2 bv = *((const float2*)(bias + lane * 2));
    int e0 = off[d], e1 = off[d + 1];
    int e = e0;
    for (; e + 4 <= e1; e += 4) {
        int2 m0 = packed[e], m1 = packed[e + 1], m2 = packed[e + 2], m3 = packed[e + 3];
        int s0 = rfl(m0.x), s1 = rfl(m1.x), s2i = rfl(m2.x), s3 = rfl(m3.x);
        float w0 = __int_as_float(rfl(m0.y)), w1 = __int_as_float(rfl(m1.y));
        float w2v = __int_as_float(rfl(m2.y)), w3 = __int_as_float(rfl(m3.y));
        unsigned v0 = *((const unsigned*)(zl + (size_t)s0 * 128));
        unsigned v1 = *((const unsigned*)(zl + (size_t)s1 * 128));
        unsigned v2 = *((const unsigned*)(zl + (size_t)s2i * 128));
        unsigned v3 = *((const unsigned*)(zl + (size_t)s3 * 128));
        acc0 = fmaf(w0, lo16(v0), acc0); acc1 = fmaf(w0, hi16(v0), acc1);
        acc0 = fmaf(w1, lo16(v1), acc0); acc1 = fmaf(w1, hi16(v1), acc1);
        acc0 = fmaf(w2v, lo16(v2), acc0); acc1 = fmaf(w2v, hi16(v2), acc1);
        acc0 = fmaf(w3, lo16(v3), acc0); acc1 = fmaf(w3, hi16(v3), acc1);
    }
    for (; e < e1; e++) {
        int2 m = packed[e];
        int s = rfl(m.x);
        float w = __int_as_float(rfl(m.y));
        unsigned v = *((const unsigned*)(zl + (size_t)s * 128));
        acc0 = fmaf(w, lo16(v), acc0);
        acc1 = fmaf(w, hi16(v), acc1);
    }
    float2 hv = {fmaxf(dv * acc0 + bv.x, 0.f), fmaxf(dv * acc1 + bv.y, 0.f)};
    *((float2*)(h + (size_t)d * 128 + lane * 2)) = hv;
}

// ---------------- agg layer2 (bf16 in) + fused dlast -----------------------
__global__ __launch_bounds__(256) void agg64_kernel(const unsigned short* __restrict__ zs2,
                                                    const int2* __restrict__ packed,
                                                    const int* __restrict__ off,
                                                    const float* __restrict__ dinv,
                                                    const float* __restrict__ bias,
                                                    float* __restrict__ o1buf, int n,
                                                    const float* __restrict__ o2,
                                                    const float* __restrict__ s2,
                                                    float* __restrict__ dlast, int N2) {
    int wid = threadIdx.x >> 6;
    int lane = threadIdx.x & 63;
    int d = rfl(blockIdx.x * 4 + wid);
    if (d >= n) return;
    const unsigned short* zl = zs2 + lane;
    float dv = dinv[d];
    float acc0 = __uint_as_float((unsigned)zl[(size_t)d * 64] << 16);
    float b0 = bias[lane];
    int e0 = off[d], e1 = off[d + 1];
    int e = e0;
    for (; e + 4 <= e1; e += 4) {
        int2 m0 = packed[e], m1 = packed[e + 1], m2 = packed[e + 2], m3 = packed[e + 3];
        int s0 = rfl(m0.x), s1 = rfl(m1.x), s2i = rfl(m2.x), s3 = rfl(m3.x);
        float w0 = __int_as_float(rfl(m0.y)), w1 = __int_as_float(rfl(m1.y));
        float w2v = __int_as_float(rfl(m2.y)), w3 = __int_as_float(rfl(m3.y));
        float v0 = __uint_as_float((unsigned)zl[(size_t)s0 * 64] << 16);
        float v1 = __uint_as_float((unsigned)zl[(size_t)s1 * 64] << 16);
        float v2 = __uint_as_float((unsigned)zl[(size_t)s2i * 64] << 16);
        float v3 = __uint_as_float((unsigned)zl[(size_t)s3 * 64] << 16);
        acc0 = fmaf(w0, v0, acc0);
        acc0 = fmaf(w1, v1, acc0);
        acc0 = fmaf(w2v, v2, acc0);
        acc0 = fmaf(w3, v3, acc0);
    }
    for (; e < e1; e++) {
        int2 m = packed[e];
        int s = rfl(m.x);
        float w = __int_as_float(rfl(m.y));
        acc0 = fmaf(w, __uint_as_float((unsigned)zl[(size_t)s * 64] << 16), acc0);
    }
    float a = fmaxf(dv * acc0 + b0, 0.f);
    o1buf[(size_t)d * 64 + lane] = a;
    float bl = o2[(size_t)(N2 - 1) * 64 + lane];
    float aa = a * a, ab = a * bl;
    for (int dd = 32; dd >= 1; dd >>= 1) {
        aa += __shfl_xor(aa, dd);
        ab += __shfl_xor(ab, dd);
    }
    if (lane == 0) {
        float d2 = aa + s2[N2 - 1] - 2.f * ab;
        dlast[d] = sqrtf(fmaxf(d2, 0.f) + 1e-12f);
    }
}

// ---------------- graph2 (row-major f32, tiny, multi-kernel) ---------------
__global__ void g2_prep(const int* __restrict__ ei2, const float* __restrict__ ew2,
                        float* dinv2, float* a2a, float* a2b, int E2, int N2) {
    __shared__ float degl[256];
    int t = threadIdx.x;
    degl[t] = 1.0f;
    __syncthreads();
    for (int e = t; e < E2; e += 256) atomicAdd(&degl[ei2[E2 + e]], ew2[e]);
    __syncthreads();
    if (t < N2) dinv2[t] = rsqrtf(degl[t]);
    for (int i = t; i < N2 * 128; i += 256) a2a[i] = 0.f;
    for (int i = t; i < N2 * 64; i += 256) a2b[i] = 0.f;
}

template <int NCOL>
__global__ void g2_gemm(const float* __restrict__ x, const float* __restrict__ w,
                        float* __restrict__ z, int N2) {
    __shared__ float xr[128];
    int row = blockIdx.x, t = threadIdx.x;
    for (int k = t; k < 128; k += NCOL) xr[k] = x[row * 128 + k];
    __syncthreads();
    float acc = 0.f;
    for (int k = 0; k < 128; k++) acc = fmaf(xr[k], w[k * NCOL + t], acc);
    z[row * NCOL + t] = acc;
}

template <int C>
__global__ void g2_scatter(const float* __restrict__ z, const int* __restrict__ ei2,
                           const float* __restrict__ ew2, const float* __restrict__ dinv2,
                           float* a2, int E2) {
    constexpr int CPL = C / 64;
    int wid = threadIdx.x >> 6, lane = threadIdx.x & 63;
    int e = blockIdx.x * 4 + wid;
    if (e >= E2) return;
    int s = ei2[e], d = ei2[E2 + e];
    float nm = dinv2[s] * ew2[e] * dinv2[d];
#pragma unroll
    for (int q = 0; q < CPL; q++) {
        int c = lane * CPL + q;
        atomicAdd(&a2[d * C + c], nm * z[s * C + c]);
    }
}

__global__ void g2_fin128(const float* __restrict__ a2, const float* __restrict__ z,
                          const float* __restrict__ dinv2, const float* __restrict__ bias,
                          float* __restrict__ out, int N2) {
    int i = blockIdx.x * 256 + threadIdx.x;
    if (i >= N2 * 128) return;
    int n = i / 128, c = i % 128;
    float dv = dinv2[n];
    out[i] = fmaxf(a2[i] + dv * dv * z[i] + bias[c], 0.f);
}

__global__ void g2_fin64s2(const float* __restrict__ a2, const float* __restrict__ z,
                           const float* __restrict__ dinv2, const float* __restrict__ bias,
                           float* __restrict__ out, float* __restrict__ s2, int N2) {
    int wid = threadIdx.x >> 6, lane = threadIdx.x & 63;
    int row = blockIdx.x * 4 + wid;
    if (row >= N2) return;
    int i = row * 64 + lane;
    float dv = dinv2[row];
    float v = fmaxf(a2[i] + dv * dv * z[i] + bias[lane], 0.f);
    out[i] = v;
    float ss = v * v;
    for (int d = 32; d >= 1; d >>= 1) ss += __shfl_xor(ss, d);
    if (lane == 0) s2[row] = ss;
}

// ---------------- top-K per graph (wave-shfl argmax, stable ties) ----------
__global__ __launch_bounds__(256) void topk_kernel(const float* __restrict__ dlast,
                                                   int* __restrict__ topidx,
                                                   int NPG, int K) {
    __shared__ unsigned long long keys[1600];
    __shared__ unsigned long long wmax[4];
    int g = blockIdx.x, t = threadIdx.x;
    int lane = t & 63, wid = t >> 6;
    for (int r = t; r < NPG; r += 256) {
        unsigned vb = __float_as_uint(dlast[(size_t)g * NPG + r]);  // dist > 0
        keys[r] = ((unsigned long long)vb << 32) | (unsigned)(NPG - 1 - r);
    }
    __syncthreads();
    for (int it = 0; it < K; it++) {
        unsigned long long m = 0ull;
        for (int r = t; r < NPG; r += 256) { unsigned long long k = keys[r]; if (k > m) m = k; }
        for (int d = 32; d >= 1; d >>= 1) {
            unsigned long long u = __shfl_xor(m, d);
            if (u > m) m = u;
        }
        if (lane == 0) wmax[wid] = m;
        __syncthreads();
        if (t == 0) {
            unsigned long long mm = wmax[0];
            for (int w = 1; w < 4; w++) if (wmax[w] > mm) mm = wmax[w];
            int rbest = NPG - 1 - (int)(mm & 0xffffffffull);
            topidx[g * K + it] = rbest;
            keys[rbest] = 0ull;
        }
        __syncthreads();
    }
}

// ---------------- pooled rows: dist(o1[sel], o2[j]) for j<N2 ---------------
__global__ void pooled_kernel(const float* __restrict__ o1, const float* __restrict__ o2,
                              const float* __restrict__ s2, const int* __restrict__ topidx,
                              float* __restrict__ pooled, int NPG, int K, int N2) {
    __shared__ float o1s[64];
    __shared__ float s1sh;
    int g = blockIdx.x / K, kk = blockIdx.x % K;
    int t = threadIdx.x;
    int r = topidx[g * K + kk];
    size_t node = (size_t)g * NPG + r;
    if (t < 64) o1s[t] = o1[node * 64 + t];
    __syncthreads();
    if (t < 64) {
        float v = o1s[t]; float ss = v * v;
        for (int d = 32; d >= 1; d >>= 1) ss += __shfl_xor(ss, d);
        if (t == 0) s1sh = ss;
    }
    __syncthreads();
    if (t < N2) {
        float dot = 0.f;
#pragma unroll 8
        for (int k2 = 0; k2 < 64; k2++) dot = fmaf(o1s[k2], o2[t * 64 + k2], dot);
        float d2 = s1sh + s2[t] - 2.f * dot;
        pooled[(size_t)blockIdx.x * N2 + t] = sqrtf(fmaxf(d2, 0.f) + 1e-12f);
    }
}

// ---------------- fc1: one block per 32-row K-chunk, all 64 graphs ---------
#define FC1_CH 32
__global__ __launch_bounds__(256) void fc1_kernel(const float* __restrict__ pooled,
                                                  const float* __restrict__ fc1W,
                                                  float* __restrict__ h1p,
                                                  int PK, int NCHUNK, int B) {
    __shared__ float ps[64][FC1_CH];
    int ch = blockIdx.x;
    int r0 = ch * FC1_CH;
    int nr = min(FC1_CH, PK - r0);
    int t = threadIdx.x;
    for (int f = t; f < 64 * FC1_CH; f += 256) {
        int b = f / FC1_CH, r = f % FC1_CH;
        ps[b][r] = (r < nr && b < B) ? pooled[(size_t)b * PK + r0 + r] : 0.f;
    }
    int c = t & 127, bh = t >> 7;
    float wreg[FC1_CH];
#pragma unroll
    for (int r = 0; r < FC1_CH; r++)
        wreg[r] = (r < nr) ? fc1W[(size_t)(r0 + r) * 128 + c] : 0.f;
    __syncthreads();
    for (int bb = 0; bb < 32; bb++) {
        int b = bh * 32 + bb;
        float acc = 0.f;
#pragma unroll
        for (int r = 0; r < FC1_CH; r++) acc = fmaf(ps[b][r], wreg[r], acc);
        if (b < B) h1p[((size_t)b * NCHUNK + ch) * 128 + c] = acc;
    }
}

// ---------------- fc1red: one wave per (b,c) output, sums NCHUNK partials --
__global__ __launch_bounds__(256) void fc1red_kernel(const float* __restrict__ h1p,
                                                     const float* __restrict__ fc1b,
                                                     float* __restrict__ h1full,
                                                     int NCHUNK, int B) {
    int wid = threadIdx.x >> 6, lane = threadIdx.x & 63;
    int o = blockIdx.x * 4 + wid;           // o in [0, B*128)
    if (o >= B * 128) return;
    int b = o >> 7, c = o & 127;
    float s = 0.f;
    for (int ch = lane; ch < NCHUNK; ch += 64)
        s += h1p[((size_t)b * NCHUNK + ch) * 128 + c];
    for (int dd = 32; dd >= 1; dd >>= 1) s += __shfl_xor(s, dd);
    if (lane == 0) h1full[o] = s + fc1b[c];
}

// ---------------- head tail (reads precomputed h1full) ---------------------
__global__ __launch_bounds__(256) void head2_kernel(
    const float* __restrict__ h1full,
    const float* __restrict__ ln1g, const float* __restrict__ ln1b,
    const float* __restrict__ fc2W, const float* __restrict__ fc2b,
    const float* __restrict__ ln2g, const float* __restrict__ ln2b,
    const float* __restrict__ fc3W, const float* __restrict__ fc3b,
    float* __restrict__ out) {
    __shared__ float red[256];
    __shared__ float h1[128];
    __shared__ float h2[64];
    int b = blockIdx.x, t = threadIdx.x;
    if (t < 128) h1[t] = h1full[b * 128 + t];
    __syncthreads();
    red[t] = (t < 128) ? h1[t] : 0.f;
    __syncthreads();
    for (int s = 128; s >= 1; s >>= 1) { if (t < s) red[t] += red[t + s]; __syncthreads(); }
    float mean1 = red[0] / 128.f;
    __syncthreads();
    float dv1 = (t < 128) ? (h1[t] - mean1) : 0.f;
    red[t] = dv1 * dv1;
    __syncthreads();
    for (int s = 128; s >= 1; s >>= 1) { if (t < s) red[t] += red[t + s]; __syncthreads(); }
    float var1 = red[0] / 128.f;
    __syncthreads();
    if (t < 128) {
        float y = (h1[t] - mean1) * rsqrtf(var1 + 1e-5f) * ln1g[t] + ln1b[t];
        h1[t] = fmaxf(y, 0.f);
    }
    __syncthreads();
    if (t < 64) {
        float a2v = 0.f;
        for (int k2 = 0; k2 < 128; k2++) a2v = fmaf(h1[k2], fc2W[k2 * 64 + t], a2v);
        h2[t] = a2v + fc2b[t];
    }
    __syncthreads();
    red[t] = (t < 64) ? h2[t] : 0.f;
    __syncthreads();
    for (int s = 128; s >= 1; s >>= 1) { if (t < s) red[t] += red[t + s]; __syncthreads(); }
    float mean2 = red[0] / 64.f;
    __syncthreads();
    float dv2 = (t < 64) ? (h2[t] - mean2) : 0.f;
    red[t] = dv2 * dv2;
    __syncthreads();
    for (int s = 128; s >= 1; s >>= 1) { if (t < s) red[t] += red[t + s]; __syncthreads(); }
    float var2 = red[0] / 64.f;
    __syncthreads();
    if (t < 64)
        h2[t] = fmaxf((h2[t] - mean2) * rsqrtf(var2 + 1e-5f) * ln2g[t] + ln2b[t], 0.f);
    __syncthreads();
    red[t] = (t < 64) ? h2[t] * fc3W[t] : 0.f;
    __syncthreads();
    for (int s = 128; s >= 1; s >>= 1) { if (t < s) red[t] += red[t + s]; __syncthreads(); }
    if (t == 0) out[b] = 1.f / (1.f + expf(-(red[0] + fc3b[0])));
}

// ---------------------------------------------------------------------------
extern "C" void kernel_launch(void* const* d_in, const int* in_sizes, int n_in,
                              void* d_out, int out_size, void* d_ws, size_t ws_size,
                              hipStream_t stream) {
    const float* x1   = (const float*)d_in[0];
    const float* ew1  = (const float*)d_in[1];
    const float* x2   = (const float*)d_in[2];
    const float* ew2  = (const float*)d_in[3];
    const float* Wg1  = (const float*)d_in[4];
    const float* bg1  = (const float*)d_in[5];
    const float* Wg2  = (const float*)d_in[6];
    const float* bg2  = (const float*)d_in[7];
    const float* fc1W = (const float*)d_in[8];
    const float* fc1b = (const float*)d_in[9];
    const float* ln1g = (const float*)d_in[10];
    const float* ln1b = (const float*)d_in[11];
    const float* fc2W = (const float*)d_in[12];
    const float* fc2b = (const float*)d_in[13];
    const float* ln2g = (const float*)d_in[14];
    const float* ln2b = (const float*)d_in[15];
    const float* fc3W = (const float*)d_in[16];
    const float* fc3b = (const float*)d_in[17];
    const int* ei1    = (const int*)d_in[18];
    const int* ei2    = (const int*)d_in[19];
    float* out = (float*)d_out;

    const int N1 = in_sizes[0] / 128;        // 102400
    const int E1 = in_sizes[1];              // 1638400
    const int N2 = in_sizes[2] / 128;        // 199
    const int E2 = in_sizes[3];              // 3184
    const int B  = out_size;                 // 64
    const int NPG = N1 / B;                  // 1600
    const int K  = (in_sizes[8] / 128) / N2; // 50
    const int PK = K * N2;                   // 9950
    const int NCHUNK = (PK + FC1_CH - 1) / FC1_CH;  // 311
    const int NBUK = (N1 + BNODES - 1) / BNODES;    // 800

    char* wsb = (char*)d_ws;
    size_t o = 0;
    auto alloc = [&](size_t bytes) -> void* {
        void* p = wsb + o;
        o += (bytes + 255) & ~(size_t)255;
        return p;
    };
    int*   bcnt   = (int*)alloc((size_t)NBUK * 4);
    int*   boff   = (int*)alloc((size_t)(NBUK + 1) * 4);
    int*   bcur   = (int*)alloc((size_t)NBUK * 4);
    int2*  stag   = (int2*)alloc((size_t)E1 * 8);
    int2*  packed = (int2*)alloc((size_t)E1 * 8);
    int*   off    = (int*)alloc((size_t)(N1 + 1) * 4);
    float* dinv1  = (float*)alloc((size_t)N1 * 4);
    unsigned short* zs1 = (unsigned short*)alloc((size_t)N1 * 128 * 2);
    float* h      = (float*)alloc((size_t)N1 * 128 * 4);
    unsigned short* zs2 = (unsigned short*)alloc((size_t)N1 * 64 * 2);
    float* o1buf  = (float*)alloc((size_t)N1 * 64 * 4);
    float* dl     = (float*)alloc((size_t)N1 * 4);
    int*   tki    = (int*)alloc((size_t)B * K * 4);
    float* pooled = (float*)alloc((size_t)B * K * N2 * 4);
    float* h1p    = (float*)alloc((size_t)B * NCHUNK * 128 * 4);
    float* h1full = (float*)alloc((size_t)B * 128 * 4);
    float* dinv2  = (float*)alloc((size_t)N2 * 4);
    float* z2g    = (float*)alloc((size_t)N2 * 128 * 4);
    float* h2b    = (float*)alloc((size_t)N2 * 128 * 4);
    float* a2a    = (float*)alloc((size_t)N2 * 128 * 4);
    float* zz2    = (float*)alloc((size_t)N2 * 64 * 4);
    float* a2b    = (float*)alloc((size_t)N2 * 64 * 4);
    float* o2b    = (float*)alloc((size_t)N2 * 64 * 4);
    float* s2     = (float*)alloc((size_t)N2 * 4);
    (void)ws_size; (void)n_in;

    const int* src1 = ei1;
    const int* dst1 = ei1 + E1;

    // -------- graph1 CSR build (radix partition) --------
    hipMemsetAsync(bcnt, 0, (size_t)NBUK * 4, stream);
    bhist_kernel<<<400, 256, 0, stream>>>(dst1, bcnt, E1, NBUK);
    bscan_kernel<<<1, 64, 0, stream>>>(bcnt, boff, bcur, off, NBUK, E1, N1);
    bpart_kernel<<<(E1 + BP_EPB - 1) / BP_EPB, 1024, 0, stream>>>(dst1, src1, ew1, bcur,
                                                                  stag, E1, NBUK);
    bfine_kernel<<<NBUK, 256, 0, stream>>>(stag, boff, packed, off, dinv1, NBUK, N1);

    // -------- graph1 layer 1 + layer-2 GEMM --------
    gemm128_kernel<<<N1 / 64, 256, 0, stream>>>(x1, Wg1, dinv1, zs1, N1);
    agg128_kernel<<<N1 / 4, 256, 0, stream>>>(zs1, packed, off, dinv1, bg1, h, N1);
    gemm64b_kernel<<<N1 / 64, 256, 0, stream>>>(h, Wg2, dinv1, zs2, N1);

    // -------- graph2 GNN (multi-kernel, parallel) --------
    g2_prep<<<1, 256, 0, stream>>>(ei2, ew2, dinv2, a2a, a2b, E2, N2);
    g2_gemm<128><<<N2, 128, 0, stream>>>(x2, Wg1, z2g, N2);
    g2_scatter<128><<<(E2 + 3) / 4, 256, 0, stream>>>(z2g, ei2, ew2, dinv2, a2a, E2);
    g2_fin128<<<(N2 * 128 + 255) / 256, 256, 0, stream>>>(a2a, z2g, dinv2, bg1, h2b, N2);
    g2_gemm<64><<<N2, 64, 0, stream>>>(h2b, Wg2, zz2, N2);
    g2_scatter<64><<<(E2 + 3) / 4, 256, 0, stream>>>(zz2, ei2, ew2, dinv2, a2b, E2);
    g2_fin64s2<<<(N2 + 3) / 4, 256, 0, stream>>>(a2b, zz2, dinv2, bg2, o2b, s2, N2);

    // -------- graph1 layer 2 agg + fused dlast --------
    agg64_kernel<<<N1 / 4, 256, 0, stream>>>(zs2, packed, off, dinv1, bg2, o1buf, N1,
                                             o2b, s2, dl, N2);

    // -------- SortAggregation + head --------
    topk_kernel<<<B, 256, 0, stream>>>(dl, tki, NPG, K);
    pooled_kernel<<<B * K, 256, 0, stream>>>(o1buf, o2b, s2, tki, pooled, NPG, K, N2);
    fc1_kernel<<<NCHUNK, 256, 0, stream>>>(pooled, fc1W, h1p, PK, NCHUNK, B);
    fc1red_kernel<<<(B * 128 + 3) / 4, 256, 0, stream>>>(h1p, fc1b, h1full, NCHUNK, B);
    head2_kernel<<<B, 256, 0, stream>>>(h1full, ln1g, ln1b, fc2W, fc2b,
                                        ln2g, ln2b, fc3W, fc3b, out);
}

// Round 15
// 418.691 us; speedup vs baseline: 1.1749x; 1.0070x over previous
//
#include <hip/hip_runtime.h>
#include <hip/hip_bf16.h>
#include <cstdint>

// ---------------------------------------------------------------------------
// SiameseGNN. R15: gemm bank-conflict fixes (6.5M conflicts in gemm128):
// (1) xs stride 68 -> 65 (was 8-way on A reads: 16*ty%32 hit 2 banks);
// (2) ws column re-grouping tx*4 + two halves (slots tile all 32 banks 2x,
// was 4-way). Math/FMA order identical -> bit-identical results.
// Keeps R14: fc1red wave-reduce, W-reuse fc1, radix CSR, bf16 rows,
// pure-gather agg128, gemm64b, fused dlast agg64.
// ---------------------------------------------------------------------------

__device__ __forceinline__ int rfl(int v) { return __builtin_amdgcn_readfirstlane(v); }

__device__ __forceinline__ unsigned short f2bf(float f) {
    unsigned u = __float_as_uint(f);
    u = (u + 0x7fffu + ((u >> 16) & 1u)) >> 16;   // RNE
    return (unsigned short)u;
}
__device__ __forceinline__ float lo16(unsigned v) { return __uint_as_float(v << 16); }
__device__ __forceinline__ float hi16(unsigned v) { return __uint_as_float(v & 0xffff0000u); }

#define BSHIFT 7
#define BNODES 128
#define BCAP 3072
#define XPAD 65

// ---------------- bhist: per-bucket edge counts (LDS-aggregated) -----------
__global__ void bhist_kernel(const int* __restrict__ dst, int* bcnt, int E, int nbuk) {
    __shared__ int bins[832];
    int t = threadIdx.x;
    for (int i = t; i < nbuk; i += 256) bins[i] = 0;
    __syncthreads();
    for (int e = blockIdx.x * 256 + t; e < E; e += gridDim.x * 256)
        atomicAdd(&bins[dst[e] >> BSHIFT], 1);
    __syncthreads();
    for (int i = t; i < nbuk; i += 256) {
        int v = bins[i];
        if (v) atomicAdd(&bcnt[i], v);
    }
}

// ---------------- bscan: bucket offsets + cursors (single wave) ------------
__global__ void bscan_kernel(const int* __restrict__ bcnt, int* __restrict__ boff,
                             int* __restrict__ bcur, int* __restrict__ off,
                             int nbuk, int E, int N1) {
    __shared__ int carry_s;
    int lane = threadIdx.x;   // 64 threads
    if (lane == 0) carry_s = 0;
    __syncthreads();
    for (int base = 0; base < nbuk; base += 64) {
        int i = base + lane;
        int v = (i < nbuk) ? bcnt[i] : 0;
        int s = v;
        for (int d2 = 1; d2 < 64; d2 <<= 1) { int u = __shfl_up(s, d2); if (lane >= d2) s += u; }
        int c = carry_s;
        if (i < nbuk) { boff[i] = c + s - v; bcur[i] = c + s - v; }
        __syncthreads();
        if (lane == 63) carry_s = c + s;
        __syncthreads();
    }
    if (lane == 0) { boff[nbuk] = E; off[N1] = E; }
}

// ---------------- bpart: partition edges into bucket-major staging ---------
#define BP_EPB 16384
__global__ __launch_bounds__(1024) void bpart_kernel(const int* __restrict__ dst,
                                                     const int* __restrict__ src,
                                                     const float* __restrict__ ew,
                                                     int* bcur, int2* __restrict__ stag,
                                                     int E, int nbuk) {
    __shared__ int cnt[832];
    __shared__ int base[832];
    int t = threadIdx.x;
    int e0 = blockIdx.x * BP_EPB;
    for (int i = t; i < nbuk; i += 1024) cnt[i] = 0;
    __syncthreads();
#pragma unroll
    for (int k = 0; k < 16; k++) {
        int e = e0 + k * 1024 + t;
        if (e < E) atomicAdd(&cnt[dst[e] >> BSHIFT], 1);
    }
    __syncthreads();
    for (int i = t; i < nbuk; i += 1024) {
        int c = cnt[i];
        base[i] = c ? atomicAdd(&bcur[i], c) : 0;
    }
    __syncthreads();
    for (int i = t; i < nbuk; i += 1024) cnt[i] = 0;
    __syncthreads();
#pragma unroll
    for (int k = 0; k < 16; k++) {
        int e = e0 + k * 1024 + t;
        if (e < E) {
            int d = dst[e];
            int b = d >> BSHIFT, dl = d & (BNODES - 1);
            int l = atomicAdd(&cnt[b], 1);
            stag[base[b] + l] = make_int2((src[e] & 0xFFFFF) | (dl << 20),
                                          __float_as_int(ew[e]));
        }
    }
}

// ---------------- bfine: bucket -> final CSR + off + dinv ------------------
__global__ __launch_bounds__(256) void bfine_kernel(const int2* __restrict__ stag,
                                                    const int* __restrict__ boff,
                                                    int2* __restrict__ packed,
                                                    int* __restrict__ off,
                                                    float* __restrict__ dinv,
                                                    int nbuk, int N1) {
    __shared__ int2 ein[BCAP];
    __shared__ int2 eout[BCAP];
    __shared__ float ews[BNODES];
    __shared__ int hist[BNODES];
    __shared__ int sb[BNODES];
    __shared__ int cnt2[BNODES];
    int b = blockIdx.x, t = threadIdx.x;
    int base = boff[b], nE = boff[b + 1] - base;
    bool staged = (nE <= BCAP);
    if (t < BNODES) { hist[t] = 0; ews[t] = 0.f; cnt2[t] = 0; }
    __syncthreads();
    if (staged)
        for (int i = t; i < nE; i += 256) ein[i] = stag[base + i];
    __syncthreads();
    for (int i = t; i < nE; i += 256) {
        int2 m = staged ? ein[i] : stag[base + i];
        int dl = m.x >> 20;
        atomicAdd(&hist[dl], 1);
        atomicAdd(&ews[dl], __int_as_float(m.y));
    }
    __syncthreads();
    if (t < 64) {
        int v0 = hist[t]; int s0 = v0;
        for (int d2 = 1; d2 < 64; d2 <<= 1) { int u = __shfl_up(s0, d2); if (t >= d2) s0 += u; }
        sb[t] = s0 - v0;
        int tot0 = __shfl(s0, 63);
        int v1 = hist[64 + t]; int s1 = v1;
        for (int d2 = 1; d2 < 64; d2 <<= 1) { int u = __shfl_up(s1, d2); if (t >= d2) s1 += u; }
        sb[64 + t] = tot0 + s1 - v1;
    }
    __syncthreads();
    int node = b * BNODES + t;
    if (t < BNODES && node < N1) {
        off[node] = base + sb[t];
        dinv[node] = rsqrtf(1.0f + ews[t]);   // +1 self loop
    }
    __syncthreads();
    for (int i = t; i < nE; i += 256) {
        int2 m = staged ? ein[i] : stag[base + i];
        int dl = m.x >> 20;
        int l = atomicAdd(&cnt2[dl], 1);
        int2 o = make_int2(m.x & 0xFFFFF, m.y);
        if (staged) eout[sb[dl] + l] = o;
        else packed[base + sb[dl] + l] = o;
    }
    __syncthreads();
    if (staged)
        for (int i = t; i < nE; i += 256) packed[base + i] = eout[i];
}

// ---------------- GEMM128: zs1 = bf16(dinv * (x @ Wg1)) --------------------
// Conflict-free: xs stride 65; thread tx owns cols {tx*4..+3} and {64+tx*4..+3}.
__global__ __launch_bounds__(256) void gemm128_kernel(const float* __restrict__ x,
                                                      const float* __restrict__ w,
                                                      const float* __restrict__ dinv,
                                                      unsigned short* __restrict__ outb,
                                                      int nrows) {
    __shared__ float ws[64 * 128];
    __shared__ float xs[64 * XPAD];
    int t = threadIdx.x;
    size_t r0 = (size_t)blockIdx.x * 64;
    int tx = t % 16, ty = t / 16;
    float acc[4][8];
#pragma unroll
    for (int i = 0; i < 4; i++)
#pragma unroll
        for (int j = 0; j < 8; j++) acc[i][j] = 0.f;

    for (int half = 0; half < 2; half++) {
        __syncthreads();
        for (int f = t; f < 64 * 32; f += 256)
            ((float4*)ws)[f] = ((const float4*)(w + half * 64 * 128))[f];
        for (int f = t; f < 64 * 16; f += 256) {
            int row = f >> 4, c4 = f & 15;
            float4 v = *((const float4*)(x + (r0 + row) * 128 + half * 64 + c4 * 4));
            xs[row * XPAD + c4 * 4]     = v.x;
            xs[row * XPAD + c4 * 4 + 1] = v.y;
            xs[row * XPAD + c4 * 4 + 2] = v.z;
            xs[row * XPAD + c4 * 4 + 3] = v.w;
        }
        __syncthreads();
        for (int k = 0; k < 64; k++) {
            float4 b0 = *((const float4*)(ws + k * 128 + tx * 4));
            float4 b1 = *((const float4*)(ws + k * 128 + 64 + tx * 4));
            float bb[8] = {b0.x, b0.y, b0.z, b0.w, b1.x, b1.y, b1.z, b1.w};
#pragma unroll
            for (int i = 0; i < 4; i++) {
                float a = xs[(ty * 4 + i) * XPAD + k];
#pragma unroll
                for (int j = 0; j < 8; j++) acc[i][j] = fmaf(a, bb[j], acc[i][j]);
            }
        }
    }
#pragma unroll
    for (int i = 0; i < 4; i++) {
        size_t row = r0 + ty * 4 + i;
        float dv = dinv[row];
        uint2 pkA, pkB;
        pkA.x = (unsigned)f2bf(acc[i][0] * dv) | ((unsigned)f2bf(acc[i][1] * dv) << 16);
        pkA.y = (unsigned)f2bf(acc[i][2] * dv) | ((unsigned)f2bf(acc[i][3] * dv) << 16);
        pkB.x = (unsigned)f2bf(acc[i][4] * dv) | ((unsigned)f2bf(acc[i][5] * dv) << 16);
        pkB.y = (unsigned)f2bf(acc[i][6] * dv) | ((unsigned)f2bf(acc[i][7] * dv) << 16);
        *((uint2*)(outb + row * 128 + tx * 4)) = pkA;
        *((uint2*)(outb + row * 128 + 64 + tx * 4)) = pkB;
    }
}

// ---------------- GEMM64b: zs2 = bf16(dinv * (h @ Wg2)), h f32 -------------
__global__ __launch_bounds__(256) void gemm64b_kernel(const float* __restrict__ x,
                                                      const float* __restrict__ w,
                                                      const float* __restrict__ dinv,
                                                      unsigned short* __restrict__ outb,
                                                      int nrows) {
    __shared__ float ws[64 * 64];
    __shared__ float xs[64 * XPAD];
    int t = threadIdx.x;
    size_t r0 = (size_t)blockIdx.x * 64;
    int tx = t % 8, ty = t / 8;    // TX=8, TY=32, AR=2
    float acc[2][8];
#pragma unroll
    for (int i = 0; i < 2; i++)
#pragma unroll
        for (int j = 0; j < 8; j++) acc[i][j] = 0.f;

    for (int half = 0; half < 2; half++) {
        __syncthreads();
        for (int f = t; f < 64 * 16; f += 256)
            ((float4*)ws)[f] = ((const float4*)(w + half * 64 * 64))[f];
        for (int f = t; f < 64 * 16; f += 256) {
            int row = f >> 4, c4 = f & 15;
            float4 v = *((const float4*)(x + (r0 + row) * 128 + half * 64 + c4 * 4));
            xs[row * XPAD + c4 * 4]     = v.x;
            xs[row * XPAD + c4 * 4 + 1] = v.y;
            xs[row * XPAD + c4 * 4 + 2] = v.z;
            xs[row * XPAD + c4 * 4 + 3] = v.w;
        }
        __syncthreads();
        for (int k = 0; k < 64; k++) {
            float4 b0 = *((const float4*)(ws + k * 64 + tx * 4));
            float4 b1 = *((const float4*)(ws + k * 64 + 32 + tx * 4));
            float bb[8] = {b0.x, b0.y, b0.z, b0.w, b1.x, b1.y, b1.z, b1.w};
#pragma unroll
            for (int i = 0; i < 2; i++) {
                float a = xs[(ty * 2 + i) * XPAD + k];
#pragma unroll
                for (int j = 0; j < 8; j++) acc[i][j] = fmaf(a, bb[j], acc[i][j]);
            }
        }
    }
#pragma unroll
    for (int i = 0; i < 2; i++) {
        size_t row = r0 + ty * 2 + i;
        float dv = dinv[row];
        uint2 pk;
        pk.x = (unsigned)f2bf(acc[i][0] * dv) | ((unsigned)f2bf(acc[i][1] * dv) << 16);
        pk.y = (unsigned)f2bf(acc[i][2] * dv) | ((unsigned)f2bf(acc[i][3] * dv) << 16);
        *((uint2*)(outb + row * 64 + tx * 4)) = pk;
        pk.x = (unsigned)f2bf(acc[i][4] * dv) | ((unsigned)f2bf(acc[i][5] * dv) << 16);
        pk.y = (unsigned)f2bf(acc[i][6] * dv) | ((unsigned)f2bf(acc[i][7] * dv) << 16);
        *((uint2*)(outb + row * 64 + 32 + tx * 4)) = pk;
    }
}

// ---------------- agg layer1: PURE gather (bf16 in) -> h f32 ---------------
__global__ __launch_bounds__(256) void agg128_kernel(const unsigned short* __restrict__ zs,
                                                     const int2* __restrict__ packed,
                                                     const int* __restrict__ off,
                                                     const float* __restrict__ dinv,
                                                     const float* __restrict__ bias,
                                                     float* __restrict__ h, int n) {
    int wid = threadIdx.x >> 6;
    int lane = threadIdx.x & 63;
    int d = rfl(blockIdx.x * 4 + wid);
    if (d >= n) return;
    const unsigned short* zl = zs + lane * 2;
    float dv = dinv[d];
    unsigned sv = *((const unsigned*)(zl + (size_t)d * 128));
    float acc0 = lo16(sv), acc1 = hi16(sv);
    float2 bv = *((const float2*)(bias + lane * 2));
    int e0 = off[d], e1 = off[d + 1];
    int e = e0;
    for (; e + 4 <= e1; e += 4) {
        int2 m0 = packed[e], m1 = packed[e + 1], m2 = packed[e + 2], m3 = packed[e + 3];
        int s0 = rfl(m0.x), s1 = rfl(m1.x), s2i = rfl(m2.x), s3 = rfl(m3.x);
        float w0 = __int_as_float(rfl(m0.y)), w1 = __int_as_float(rfl(m1.y));
        float w2v = __int_as_float(rfl(m2.y)), w3 = __int_as_float(rfl(m3.y));
        unsigned v0 = *((const unsigned*)(zl + (size_t)s0 * 128));
        unsigned v1 = *((const unsigned*)(zl + (size_t)s1 * 128));
        unsigned v2 = *((const unsigned*)(zl + (size_t)s2i * 128));
        unsigned v3 = *((const unsigned*)(zl + (size_t)s3 * 128));
        acc0 = fmaf(w0, lo16(v0), acc0); acc1 = fmaf(w0, hi16(v0), acc1);
        acc0 = fmaf(w1, lo16(v1), acc0); acc1 = fmaf(w1, hi16(v1), acc1);
        acc0 = fmaf(w2v, lo16(v2), acc0); acc1 = fmaf(w2v, hi16(v2), acc1);
        acc0 = fmaf(w3, lo16(v3), acc0); acc1 = fmaf(w3, hi16(v3), acc1);
    }
    for (; e < e1; e++) {
        int2 m = packed[e];
        int s = rfl(m.x);
        float w = __int_as_float(rfl(m.y));
        unsigned v = *((const unsigned*)(zl + (size_t)s * 128));
        acc0 = fmaf(w, lo16(v), acc0);
        acc1 = fmaf(w, hi16(v), acc1);
    }
    float2 hv = {fmaxf(dv * acc0 + bv.x, 0.f), fmaxf(dv * acc1 + bv.y, 0.f)};
    *((float2*)(h + (size_t)d * 128 + lane * 2)) = hv;
}

// ---------------- agg layer2 (bf16 in) + fused dlast -----------------------
__global__ __launch_bounds__(256) void agg64_kernel(const unsigned short* __restrict__ zs2,
                                                    const int2* __restrict__ packed,
                                                    const int* __restrict__ off,
                                                    const float* __restrict__ dinv,
                                                    const float* __restrict__ bias,
                                                    float* __restrict__ o1buf, int n,
                                                    const float* __restrict__ o2,
                                                    const float* __restrict__ s2,
                                                    float* __restrict__ dlast, int N2) {
    int wid = threadIdx.x >> 6;
    int lane = threadIdx.x & 63;
    int d = rfl(blockIdx.x * 4 + wid);
    if (d >= n) return;
    const unsigned short* zl = zs2 + lane;
    float dv = dinv[d];
    float acc0 = __uint_as_float((unsigned)zl[(size_t)d * 64] << 16);
    float b0 = bias[lane];
    int e0 = off[d], e1 = off[d + 1];
    int e = e0;
    for (; e + 4 <= e1; e += 4) {
        int2 m0 = packed[e], m1 = packed[e + 1], m2 = packed[e + 2], m3 = packed[e + 3];
        int s0 = rfl(m0.x), s1 = rfl(m1.x), s2i = rfl(m2.x), s3 = rfl(m3.x);
        float w0 = __int_as_float(rfl(m0.y)), w1 = __int_as_float(rfl(m1.y));
        float w2v = __int_as_float(rfl(m2.y)), w3 = __int_as_float(rfl(m3.y));
        float v0 = __uint_as_float((unsigned)zl[(size_t)s0 * 64] << 16);
        float v1 = __uint_as_float((unsigned)zl[(size_t)s1 * 64] << 16);
        float v2 = __uint_as_float((unsigned)zl[(size_t)s2i * 64] << 16);
        float v3 = __uint_as_float((unsigned)zl[(size_t)s3 * 64] << 16);
        acc0 = fmaf(w0, v0, acc0);
        acc0 = fmaf(w1, v1, acc0);
        acc0 = fmaf(w2v, v2, acc0);
        acc0 = fmaf(w3, v3, acc0);
    }
    for (; e < e1; e++) {
        int2 m = packed[e];
        int s = rfl(m.x);
        float w = __int_as_float(rfl(m.y));
        acc0 = fmaf(w, __uint_as_float((unsigned)zl[(size_t)s * 64] << 16), acc0);
    }
    float a = fmaxf(dv * acc0 + b0, 0.f);
    o1buf[(size_t)d * 64 + lane] = a;
    float bl = o2[(size_t)(N2 - 1) * 64 + lane];
    float aa = a * a, ab = a * bl;
    for (int dd = 32; dd >= 1; dd >>= 1) {
        aa += __shfl_xor(aa, dd);
        ab += __shfl_xor(ab, dd);
    }
    if (lane == 0) {
        float d2 = aa + s2[N2 - 1] - 2.f * ab;
        dlast[d] = sqrtf(fmaxf(d2, 0.f) + 1e-12f);
    }
}

// ---------------- graph2 (row-major f32, tiny, multi-kernel) ---------------
__global__ void g2_prep(const int* __restrict__ ei2, const float* __restrict__ ew2,
                        float* dinv2, float* a2a, float* a2b, int E2, int N2) {
    __shared__ float degl[256];
    int t = threadIdx.x;
    degl[t] = 1.0f;
    __syncthreads();
    for (int e = t; e < E2; e += 256) atomicAdd(&degl[ei2[E2 + e]], ew2[e]);
    __syncthreads();
    if (t < N2) dinv2[t] = rsqrtf(degl[t]);
    for (int i = t; i < N2 * 128; i += 256) a2a[i] = 0.f;
    for (int i = t; i < N2 * 64; i += 256) a2b[i] = 0.f;
}

template <int NCOL>
__global__ void g2_gemm(const float* __restrict__ x, const float* __restrict__ w,
                        float* __restrict__ z, int N2) {
    __shared__ float xr[128];
    int row = blockIdx.x, t = threadIdx.x;
    for (int k = t; k < 128; k += NCOL) xr[k] = x[row * 128 + k];
    __syncthreads();
    float acc = 0.f;
    for (int k = 0; k < 128; k++) acc = fmaf(xr[k], w[k * NCOL + t], acc);
    z[row * NCOL + t] = acc;
}

template <int C>
__global__ void g2_scatter(const float* __restrict__ z, const int* __restrict__ ei2,
                           const float* __restrict__ ew2, const float* __restrict__ dinv2,
                           float* a2, int E2) {
    constexpr int CPL = C / 64;
    int wid = threadIdx.x >> 6, lane = threadIdx.x & 63;
    int e = blockIdx.x * 4 + wid;
    if (e >= E2) return;
    int s = ei2[e], d = ei2[E2 + e];
    float nm = dinv2[s] * ew2[e] * dinv2[d];
#pragma unroll
    for (int q = 0; q < CPL; q++) {
        int c = lane * CPL + q;
        atomicAdd(&a2[d * C + c], nm * z[s * C + c]);
    }
}

__global__ void g2_fin128(const float* __restrict__ a2, const float* __restrict__ z,
                          const float* __restrict__ dinv2, const float* __restrict__ bias,
                          float* __restrict__ out, int N2) {
    int i = blockIdx.x * 256 + threadIdx.x;
    if (i >= N2 * 128) return;
    int n = i / 128, c = i % 128;
    float dv = dinv2[n];
    out[i] = fmaxf(a2[i] + dv * dv * z[i] + bias[c], 0.f);
}

__global__ void g2_fin64s2(const float* __restrict__ a2, const float* __restrict__ z,
                           const float* __restrict__ dinv2, const float* __restrict__ bias,
                           float* __restrict__ out, float* __restrict__ s2, int N2) {
    int wid = threadIdx.x >> 6, lane = threadIdx.x & 63;
    int row = blockIdx.x * 4 + wid;
    if (row >= N2) return;
    int i = row * 64 + lane;
    float dv = dinv2[row];
    float v = fmaxf(a2[i] + dv * dv * z[i] + bias[lane], 0.f);
    out[i] = v;
    float ss = v * v;
    for (int d = 32; d >= 1; d >>= 1) ss += __shfl_xor(ss, d);
    if (lane == 0) s2[row] = ss;
}

// ---------------- top-K per graph (wave-shfl argmax, stable ties) ----------
__global__ __launch_bounds__(256) void topk_kernel(const float* __restrict__ dlast,
                                                   int* __restrict__ topidx,
                                                   int NPG, int K) {
    __shared__ unsigned long long keys[1600];
    __shared__ unsigned long long wmax[4];
    int g = blockIdx.x, t = threadIdx.x;
    int lane = t & 63, wid = t >> 6;
    for (int r = t; r < NPG; r += 256) {
        unsigned vb = __float_as_uint(dlast[(size_t)g * NPG + r]);  // dist > 0
        keys[r] = ((unsigned long long)vb << 32) | (unsigned)(NPG - 1 - r);
    }
    __syncthreads();
    for (int it = 0; it < K; it++) {
        unsigned long long m = 0ull;
        for (int r = t; r < NPG; r += 256) { unsigned long long k = keys[r]; if (k > m) m = k; }
        for (int d = 32; d >= 1; d >>= 1) {
            unsigned long long u = __shfl_xor(m, d);
            if (u > m) m = u;
        }
        if (lane == 0) wmax[wid] = m;
        __syncthreads();
        if (t == 0) {
            unsigned long long mm = wmax[0];
            for (int w = 1; w < 4; w++) if (wmax[w] > mm) mm = wmax[w];
            int rbest = NPG - 1 - (int)(mm & 0xffffffffull);
            topidx[g * K + it] = rbest;
            keys[rbest] = 0ull;
        }
        __syncthreads();
    }
}

// ---------------- pooled rows: dist(o1[sel], o2[j]) for j<N2 ---------------
__global__ void pooled_kernel(const float* __restrict__ o1, const float* __restrict__ o2,
                              const float* __restrict__ s2, const int* __restrict__ topidx,
                              float* __restrict__ pooled, int NPG, int K, int N2) {
    __shared__ float o1s[64];
    __shared__ float s1sh;
    int g = blockIdx.x / K, kk = blockIdx.x % K;
    int t = threadIdx.x;
    int r = topidx[g * K + kk];
    size_t node = (size_t)g * NPG + r;
    if (t < 64) o1s[t] = o1[node * 64 + t];
    __syncthreads();
    if (t < 64) {
        float v = o1s[t]; float ss = v * v;
        for (int d = 32; d >= 1; d >>= 1) ss += __shfl_xor(ss, d);
        if (t == 0) s1sh = ss;
    }
    __syncthreads();
    if (t < N2) {
        float dot = 0.f;
#pragma unroll 8
        for (int k2 = 0; k2 < 64; k2++) dot = fmaf(o1s[k2], o2[t * 64 + k2], dot);
        float d2 = s1sh + s2[t] - 2.f * dot;
        pooled[(size_t)blockIdx.x * N2 + t] = sqrtf(fmaxf(d2, 0.f) + 1e-12f);
    }
}

// ---------------- fc1: one block per 32-row K-chunk, all 64 graphs ---------
#define FC1_CH 32
__global__ __launch_bounds__(256) void fc1_kernel(const float* __restrict__ pooled,
                                                  const float* __restrict__ fc1W,
                                                  float* __restrict__ h1p,
                                                  int PK, int NCHUNK, int B) {
    __shared__ float ps[64][FC1_CH];
    int ch = blockIdx.x;
    int r0 = ch * FC1_CH;
    int nr = min(FC1_CH, PK - r0);
    int t = threadIdx.x;
    for (int f = t; f < 64 * FC1_CH; f += 256) {
        int b = f / FC1_CH, r = f % FC1_CH;
        ps[b][r] = (r < nr && b < B) ? pooled[(size_t)b * PK + r0 + r] : 0.f;
    }
    int c = t & 127, bh = t >> 7;
    float wreg[FC1_CH];
#pragma unroll
    for (int r = 0; r < FC1_CH; r++)
        wreg[r] = (r < nr) ? fc1W[(size_t)(r0 + r) * 128 + c] : 0.f;
    __syncthreads();
    for (int bb = 0; bb < 32; bb++) {
        int b = bh * 32 + bb;
        float acc = 0.f;
#pragma unroll
        for (int r = 0; r < FC1_CH; r++) acc = fmaf(ps[b][r], wreg[r], acc);
        if (b < B) h1p[((size_t)b * NCHUNK + ch) * 128 + c] = acc;
    }
}

// ---------------- fc1red: one wave per (b,c) output, sums NCHUNK partials --
__global__ __launch_bounds__(256) void fc1red_kernel(const float* __restrict__ h1p,
                                                     const float* __restrict__ fc1b,
                                                     float* __restrict__ h1full,
                                                     int NCHUNK, int B) {
    int wid = threadIdx.x >> 6, lane = threadIdx.x & 63;
    int o = blockIdx.x * 4 + wid;           // o in [0, B*128)
    if (o >= B * 128) return;
    int b = o >> 7, c = o & 127;
    float s = 0.f;
    for (int ch = lane; ch < NCHUNK; ch += 64)
        s += h1p[((size_t)b * NCHUNK + ch) * 128 + c];
    for (int dd = 32; dd >= 1; dd >>= 1) s += __shfl_xor(s, dd);
    if (lane == 0) h1full[o] = s + fc1b[c];
}

// ---------------- head tail (reads precomputed h1full) ---------------------
__global__ __launch_bounds__(256) void head2_kernel(
    const float* __restrict__ h1full,
    const float* __restrict__ ln1g, const float* __restrict__ ln1b,
    const float* __restrict__ fc2W, const float* __restrict__ fc2b,
    const float* __restrict__ ln2g, const float* __restrict__ ln2b,
    const float* __restrict__ fc3W, const float* __restrict__ fc3b,
    float* __restrict__ out) {
    __shared__ float red[256];
    __shared__ float h1[128];
    __shared__ float h2[64];
    int b = blockIdx.x, t = threadIdx.x;
    if (t < 128) h1[t] = h1full[b * 128 + t];
    __syncthreads();
    red[t] = (t < 128) ? h1[t] : 0.f;
    __syncthreads();
    for (int s = 128; s >= 1; s >>= 1) { if (t < s) red[t] += red[t + s]; __syncthreads(); }
    float mean1 = red[0] / 128.f;
    __syncthreads();
    float dv1 = (t < 128) ? (h1[t] - mean1) : 0.f;
    red[t] = dv1 * dv1;
    __syncthreads();
    for (int s = 128; s >= 1; s >>= 1) { if (t < s) red[t] += red[t + s]; __syncthreads(); }
    float var1 = red[0] / 128.f;
    __syncthreads();
    if (t < 128) {
        float y = (h1[t] - mean1) * rsqrtf(var1 + 1e-5f) * ln1g[t] + ln1b[t];
        h1[t] = fmaxf(y, 0.f);
    }
    __syncthreads();
    if (t < 64) {
        float a2v = 0.f;
        for (int k2 = 0; k2 < 128; k2++) a2v = fmaf(h1[k2], fc2W[k2 * 64 + t], a2v);
        h2[t] = a2v + fc2b[t];
    }
    __syncthreads();
    red[t] = (t < 64) ? h2[t] : 0.f;
    __syncthreads();
    for (int s = 128; s >= 1; s >>= 1) { if (t < s) red[t] += red[t + s]; __syncthreads(); }
    float mean2 = red[0] / 64.f;
    __syncthreads();
    float dv2 = (t < 64) ? (h2[t] - mean2) : 0.f;
    red[t] = dv2 * dv2;
    __syncthreads();
    for (int s = 128; s >= 1; s >>= 1) { if (t < s) red[t] += red[t + s]; __syncthreads(); }
    float var2 = red[0] / 64.f;
    __syncthreads();
    if (t < 64)
        h2[t] = fmaxf((h2[t] - mean2) * rsqrtf(var2 + 1e-5f) * ln2g[t] + ln2b[t], 0.f);
    __syncthreads();
    red[t] = (t < 64) ? h2[t] * fc3W[t] : 0.f;
    __syncthreads();
    for (int s = 128; s >= 1; s >>= 1) { if (t < s) red[t] += red[t + s]; __syncthreads(); }
    if (t == 0) out[b] = 1.f / (1.f + expf(-(red[0] + fc3b[0])));
}

// ---------------------------------------------------------------------------
extern "C" void kernel_launch(void* const* d_in, const int* in_sizes, int n_in,
                              void* d_out, int out_size, void* d_ws, size_t ws_size,
                              hipStream_t stream) {
    const float* x1   = (const float*)d_in[0];
    const float* ew1  = (const float*)d_in[1];
    const float* x2   = (const float*)d_in[2];
    const float* ew2  = (const float*)d_in[3];
    const float* Wg1  = (const float*)d_in[4];
    const float* bg1  = (const float*)d_in[5];
    const float* Wg2  = (const float*)d_in[6];
    const float* bg2  = (const float*)d_in[7];
    const float* fc1W = (const float*)d_in[8];
    const float* fc1b = (const float*)d_in[9];
    const float* ln1g = (const float*)d_in[10];
    const float* ln1b = (const float*)d_in[11];
    const float* fc2W = (const float*)d_in[12];
    const float* fc2b = (const float*)d_in[13];
    const float* ln2g = (const float*)d_in[14];
    const float* ln2b = (const float*)d_in[15];
    const float* fc3W = (const float*)d_in[16];
    const float* fc3b = (const float*)d_in[17];
    const int* ei1    = (const int*)d_in[18];
    const int* ei2    = (const int*)d_in[19];
    float* out = (float*)d_out;

    const int N1 = in_sizes[0] / 128;        // 102400
    const int E1 = in_sizes[1];              // 1638400
    const int N2 = in_sizes[2] / 128;        // 199
    const int E2 = in_sizes[3];              // 3184
    const int B  = out_size;                 // 64
    const int NPG = N1 / B;                  // 1600
    const int K  = (in_sizes[8] / 128) / N2; // 50
    const int PK = K * N2;                   // 9950
    const int NCHUNK = (PK + FC1_CH - 1) / FC1_CH;  // 311
    const int NBUK = (N1 + BNODES - 1) / BNODES;    // 800

    char* wsb = (char*)d_ws;
    size_t o = 0;
    auto alloc = [&](size_t bytes) -> void* {
        void* p = wsb + o;
        o += (bytes + 255) & ~(size_t)255;
        return p;
    };
    int*   bcnt   = (int*)alloc((size_t)NBUK * 4);
    int*   boff   = (int*)alloc((size_t)(NBUK + 1) * 4);
    int*   bcur   = (int*)alloc((size_t)NBUK * 4);
    int2*  stag   = (int2*)alloc((size_t)E1 * 8);
    int2*  packed = (int2*)alloc((size_t)E1 * 8);
    int*   off    = (int*)alloc((size_t)(N1 + 1) * 4);
    float* dinv1  = (float*)alloc((size_t)N1 * 4);
    unsigned short* zs1 = (unsigned short*)alloc((size_t)N1 * 128 * 2);
    float* h      = (float*)alloc((size_t)N1 * 128 * 4);
    unsigned short* zs2 = (unsigned short*)alloc((size_t)N1 * 64 * 2);
    float* o1buf  = (float*)alloc((size_t)N1 * 64 * 4);
    float* dl     = (float*)alloc((size_t)N1 * 4);
    int*   tki    = (int*)alloc((size_t)B * K * 4);
    float* pooled = (float*)alloc((size_t)B * K * N2 * 4);
    float* h1p    = (float*)alloc((size_t)B * NCHUNK * 128 * 4);
    float* h1full = (float*)alloc((size_t)B * 128 * 4);
    float* dinv2  = (float*)alloc((size_t)N2 * 4);
    float* z2g    = (float*)alloc((size_t)N2 * 128 * 4);
    float* h2b    = (float*)alloc((size_t)N2 * 128 * 4);
    float* a2a    = (float*)alloc((size_t)N2 * 128 * 4);
    float* zz2    = (float*)alloc((size_t)N2 * 64 * 4);
    float* a2b    = (float*)alloc((size_t)N2 * 64 * 4);
    float* o2b    = (float*)alloc((size_t)N2 * 64 * 4);
    float* s2     = (float*)alloc((size_t)N2 * 4);
    (void)ws_size; (void)n_in;

    const int* src1 = ei1;
    const int* dst1 = ei1 + E1;

    // -------- graph1 CSR build (radix partition) --------
    hipMemsetAsync(bcnt, 0, (size_t)NBUK * 4, stream);
    bhist_kernel<<<400, 256, 0, stream>>>(dst1, bcnt, E1, NBUK);
    bscan_kernel<<<1, 64, 0, stream>>>(bcnt, boff, bcur, off, NBUK, E1, N1);
    bpart_kernel<<<(E1 + BP_EPB - 1) / BP_EPB, 1024, 0, stream>>>(dst1, src1, ew1, bcur,
                                                                  stag, E1, NBUK);
    bfine_kernel<<<NBUK, 256, 0, stream>>>(stag, boff, packed, off, dinv1, NBUK, N1);

    // -------- graph1 layer 1 + layer-2 GEMM --------
    gemm128_kernel<<<N1 / 64, 256, 0, stream>>>(x1, Wg1, dinv1, zs1, N1);
    agg128_kernel<<<N1 / 4, 256, 0, stream>>>(zs1, packed, off, dinv1, bg1, h, N1);
    gemm64b_kernel<<<N1 / 64, 256, 0, stream>>>(h, Wg2, dinv1, zs2, N1);

    // -------- graph2 GNN (multi-kernel, parallel) --------
    g2_prep<<<1, 256, 0, stream>>>(ei2, ew2, dinv2, a2a, a2b, E2, N2);
    g2_gemm<128><<<N2, 128, 0, stream>>>(x2, Wg1, z2g, N2);
    g2_scatter<128><<<(E2 + 3) / 4, 256, 0, stream>>>(z2g, ei2, ew2, dinv2, a2a, E2);
    g2_fin128<<<(N2 * 128 + 255) / 256, 256, 0, stream>>>(a2a, z2g, dinv2, bg1, h2b, N2);
    g2_gemm<64><<<N2, 64, 0, stream>>>(h2b, Wg2, zz2, N2);
    g2_scatter<64><<<(E2 + 3) / 4, 256, 0, stream>>>(zz2, ei2, ew2, dinv2, a2b, E2);
    g2_fin64s2<<<(N2 + 3) / 4, 256, 0, stream>>>(a2b, zz2, dinv2, bg2, o2b, s2, N2);

    // -------- graph1 layer 2 agg + fused dlast --------
    agg64_kernel<<<N1 / 4, 256, 0, stream>>>(zs2, packed, off, dinv1, bg2, o1buf, N1,
                                             o2b, s2, dl, N2);

    // -------- SortAggregation + head --------
    topk_kernel<<<B, 256, 0, stream>>>(dl, tki, NPG, K);
    pooled_kernel<<<B * K, 256, 0, stream>>>(o1buf, o2b, s2, tki, pooled, NPG, K, N2);
    fc1_kernel<<<NCHUNK, 256, 0, stream>>>(pooled, fc1W, h1p, PK, NCHUNK, B);
    fc1red_kernel<<<(B * 128 + 3) / 4, 256, 0, stream>>>(h1p, fc1b, h1full, NCHUNK, B);
    head2_kernel<<<B, 256, 0, stream>>>(h1full, ln1g, ln1b, fc2W, fc2b,
                                        ln2g, ln2b, fc3W, fc3b, out);
}